// Round 1
// baseline (763.329 us; speedup 1.0000x reference)
//
#include <hip/hip_runtime.h>

#define BATCH 4
#define SLEN 2048
#define DMODEL 1024
#define NHEADS 16
#define DK 64
#define MROWS (BATCH * SLEN)  // 8192

typedef short bf16x8 __attribute__((ext_vector_type(8)));
typedef unsigned short u16x4 __attribute__((ext_vector_type(4)));
typedef float f32x4 __attribute__((ext_vector_type(4)));

// ---- fp32 -> bf16 (round-to-nearest-even), bit-level so no header struct issues ----
__device__ __forceinline__ unsigned short f2bf(float f) {
    unsigned u = __float_as_uint(f);
    unsigned r = u + 0x7FFFu + ((u >> 16) & 1u);
    return (unsigned short)(r >> 16);
}
__device__ __forceinline__ float bf2f(unsigned short b) {
    return __uint_as_float(((unsigned)b) << 16);
}

__global__ void cvt_f32_bf16(const float* __restrict__ in, unsigned short* __restrict__ out, int n) {
    int i = (blockIdx.x * blockDim.x + threadIdx.x) * 4;
    if (i >= n) return;
    float4 v = *reinterpret_cast<const float4*>(in + i);
    u16x4 o;
    o[0] = f2bf(v.x); o[1] = f2bf(v.y); o[2] = f2bf(v.z); o[3] = f2bf(v.w);
    *reinterpret_cast<u16x4*>(out + i) = o;
}

// ---- RoPE cos/sin table: [SLEN][32] each ----
__global__ void rope_table(const int* __restrict__ tok, float* __restrict__ cs, float* __restrict__ sn) {
    int idx = blockIdx.x * blockDim.x + threadIdx.x;  // 0..65535
    if (idx >= SLEN * 32) return;
    int s = idx >> 5, fi = idx & 31;
    float invf = powf(10000.0f, -(float)(2 * fi) / 64.0f);
    float ang = (float)tok[s] * invf;
    cs[idx] = cosf(ang);
    sn[idx] = sinf(ang);
}

// ---- Fused QKV projection GEMM + RoPE epilogue ----
// X: [8192][1024] bf16 row-major.  W*: [1024][1024] bf16 row-major (n-major = B^T form).
// z=0 -> Q[B][H][S][DK] (rope), z=1 -> K[B][H][S][DK] (rope), z=2 -> VT[B][H][DK][S].
__global__ __launch_bounds__(256) void qkv_gemm(
    const unsigned short* __restrict__ X,
    const unsigned short* __restrict__ Wq,
    const unsigned short* __restrict__ Wk,
    const unsigned short* __restrict__ Wv,
    const float* __restrict__ cs_tab, const float* __restrict__ sn_tab,
    unsigned short* __restrict__ Q, unsigned short* __restrict__ K,
    unsigned short* __restrict__ VT)
{
    int tid = threadIdx.x, lane = tid & 63, wave = tid >> 6;
    int ln = lane & 15, kq = lane >> 4;
    int wr = wave >> 1, wc = wave & 1;
    int m0 = blockIdx.x * 128 + wr * 64;
    int n0 = blockIdx.y * 128 + wc * 64;
    int z = blockIdx.z;
    const unsigned short* W = (z == 0) ? Wq : (z == 1) ? Wk : Wv;

    f32x4 acc[4][4];
    for (int a = 0; a < 4; a++)
        for (int b = 0; b < 4; b++)
            acc[a][b] = (f32x4){0.f, 0.f, 0.f, 0.f};

    const unsigned short* Abase = X + (size_t)(m0 + ln) * DMODEL + kq * 8;
    const unsigned short* Bbase = W + (size_t)(n0 + ln) * DMODEL + kq * 8;

    for (int k0 = 0; k0 < DMODEL; k0 += 32) {
        bf16x8 af[4], bfr[4];
#pragma unroll
        for (int mt = 0; mt < 4; mt++)
            af[mt] = *reinterpret_cast<const bf16x8*>(Abase + (size_t)mt * 16 * DMODEL + k0);
#pragma unroll
        for (int nt = 0; nt < 4; nt++)
            bfr[nt] = *reinterpret_cast<const bf16x8*>(Bbase + (size_t)nt * 16 * DMODEL + k0);
#pragma unroll
        for (int mt = 0; mt < 4; mt++)
#pragma unroll
            for (int nt = 0; nt < 4; nt++)
                acc[mt][nt] = __builtin_amdgcn_mfma_f32_16x16x32_bf16(af[mt], bfr[nt], acc[mt][nt], 0, 0, 0);
    }

    bool isV = (z == 2);
    unsigned short* dstQK = (z == 0) ? Q : K;
#pragma unroll
    for (int nt = 0; nt < 4; nt++) {
        int n = n0 + nt * 16 + ln;
        int h = n >> 6, d = n & 63;
        int fi = d >> 1;
#pragma unroll
        for (int mt = 0; mt < 4; mt++) {
#pragma unroll
            for (int j = 0; j < 4; j++) {
                int m = m0 + mt * 16 + kq * 4 + j;
                int b = m >> 11, s = m & (SLEN - 1);
                float v = acc[mt][nt][j];
                if (!isV) {
                    float c = cs_tab[s * 32 + fi];
                    float si = sn_tab[s * 32 + fi];
                    float p = __shfl_xor(v, 1);
                    v = (d & 1) ? (p * si + v * c) : (v * c - p * si);
                    dstQK[(((size_t)(b * NHEADS + h) * SLEN + s) << 6) + d] = f2bf(v);
                } else {
                    VT[((size_t)(b * NHEADS + h) * DK + d) * SLEN + s] = f2bf(v);
                }
            }
        }
    }
}

// ---- Causal flash attention ----
// Q,K: [B*H][S][64] bf16; VT: [B*H][64][S] bf16; O: [B][S][D] bf16.
// Block: 4 waves; 64 q-rows per block (16 per wave); KV tiles of 64.
__global__ __launch_bounds__(256) void attn_kernel(
    const unsigned short* __restrict__ Q, const unsigned short* __restrict__ K,
    const unsigned short* __restrict__ VT, unsigned short* __restrict__ O)
{
    __shared__ alignas(16) unsigned short P_lds[4][16][72];  // padded stride 72
    int tid = threadIdx.x, lane = tid & 63, wave = tid >> 6;
    int ln = lane & 15, kq = lane >> 4;
    int q0b = blockIdx.x * 64;
    int h = blockIdx.y, b = blockIdx.z;
    size_t headoff = ((size_t)b * NHEADS + h) * SLEN * DK;
    const unsigned short* Qh = Q + headoff;
    const unsigned short* Kh = K + headoff;
    const unsigned short* Vh = VT + headoff;  // [64][S]
    int q0 = q0b + wave * 16;

    bf16x8 aq[2];
#pragma unroll
    for (int kc = 0; kc < 2; kc++)
        aq[kc] = *reinterpret_cast<const bf16x8*>(Qh + (size_t)(q0 + ln) * DK + kc * 32 + kq * 8);

    f32x4 oacc[4];
#pragma unroll
    for (int nt = 0; nt < 4; nt++) oacc[nt] = (f32x4){0.f, 0.f, 0.f, 0.f};
    float m_r[4], l_r[4];
#pragma unroll
    for (int j = 0; j < 4; j++) { m_r[j] = -1e30f; l_r[j] = 0.f; }

    int tmax = (q0 + 15) >> 6;  // same for all 4 waves of the block
    for (int t = 0; t <= tmax; ++t) {
        int kv0 = t << 6;
        f32x4 sacc[4];
#pragma unroll
        for (int nt = 0; nt < 4; nt++) sacc[nt] = (f32x4){0.f, 0.f, 0.f, 0.f};
#pragma unroll
        for (int nt = 0; nt < 4; nt++) {
#pragma unroll
            for (int kc = 0; kc < 2; kc++) {
                bf16x8 bk = *reinterpret_cast<const bf16x8*>(
                    Kh + (size_t)(kv0 + nt * 16 + ln) * DK + kc * 32 + kq * 8);
                sacc[nt] = __builtin_amdgcn_mfma_f32_16x16x32_bf16(aq[kc], bk, sacc[nt], 0, 0, 0);
            }
        }
        // scale + causal mask (only diagonal tile needs it)
        bool diag = (t == tmax);
#pragma unroll
        for (int nt = 0; nt < 4; nt++) {
#pragma unroll
            for (int j = 0; j < 4; j++) {
                float v = sacc[nt][j] * 0.125f;
                if (diag) {
                    int col = kv0 + nt * 16 + ln;
                    int row = q0 + kq * 4 + j;
                    if (col > row) v = -1e30f;
                }
                sacc[nt][j] = v;
            }
        }
        // wave-parallel row max (rows live on 16-lane groups)
        float mloc[4];
#pragma unroll
        for (int j = 0; j < 4; j++)
            mloc[j] = fmaxf(fmaxf(sacc[0][j], sacc[1][j]), fmaxf(sacc[2][j], sacc[3][j]));
#pragma unroll
        for (int off = 1; off < 16; off <<= 1)
#pragma unroll
            for (int j = 0; j < 4; j++)
                mloc[j] = fmaxf(mloc[j], __shfl_xor(mloc[j], off));

        float so[4];
#pragma unroll
        for (int j = 0; j < 4; j++) {
            float mn = fmaxf(m_r[j], mloc[j]);
            so[j] = __expf(m_r[j] - mn);
            m_r[j] = mn;
        }
        float rs[4] = {0.f, 0.f, 0.f, 0.f};
#pragma unroll
        for (int nt = 0; nt < 4; nt++)
#pragma unroll
            for (int j = 0; j < 4; j++) {
                float p = __expf(sacc[nt][j] - m_r[j]);
                sacc[nt][j] = p;
                rs[j] += p;
            }
#pragma unroll
        for (int off = 1; off < 16; off <<= 1)
#pragma unroll
            for (int j = 0; j < 4; j++)
                rs[j] += __shfl_xor(rs[j], off);
#pragma unroll
        for (int j = 0; j < 4; j++) l_r[j] = l_r[j] * so[j] + rs[j];
#pragma unroll
        for (int nt = 0; nt < 4; nt++)
#pragma unroll
            for (int j = 0; j < 4; j++)
                oacc[nt][j] *= so[j];

        // stage P (bf16) through per-wave LDS to get PV A-fragment layout
#pragma unroll
        for (int nt = 0; nt < 4; nt++)
#pragma unroll
            for (int j = 0; j < 4; j++)
                P_lds[wave][kq * 4 + j][nt * 16 + ln] = f2bf(sacc[nt][j]);
        __syncthreads();

        bf16x8 pa[2];
#pragma unroll
        for (int kc = 0; kc < 2; kc++)
            pa[kc] = *reinterpret_cast<const bf16x8*>(&P_lds[wave][ln][kc * 32 + kq * 8]);

#pragma unroll
        for (int nt = 0; nt < 4; nt++) {
#pragma unroll
            for (int kc = 0; kc < 2; kc++) {
                bf16x8 bv = *reinterpret_cast<const bf16x8*>(
                    Vh + (size_t)(nt * 16 + ln) * SLEN + kv0 + kc * 32 + kq * 8);
                oacc[nt] = __builtin_amdgcn_mfma_f32_16x16x32_bf16(pa[kc], bv, oacc[nt], 0, 0, 0);
            }
        }
        __syncthreads();
    }

    // epilogue: O[b][s][h*64+d] bf16
#pragma unroll
    for (int nt = 0; nt < 4; nt++)
#pragma unroll
        for (int j = 0; j < 4; j++) {
            int row = q0 + kq * 4 + j;
            float v = oacc[nt][j] / l_r[j];
            O[((size_t)b * SLEN + row) * DMODEL + h * 64 + nt * 16 + ln] = f2bf(v);
        }
}

// ---- Output projection: out = O @ Wo^T, fp32 result ----
__global__ __launch_bounds__(256) void out_gemm(
    const unsigned short* __restrict__ A, const unsigned short* __restrict__ Wo,
    float* __restrict__ out)
{
    int tid = threadIdx.x, lane = tid & 63, wave = tid >> 6;
    int ln = lane & 15, kq = lane >> 4;
    int wr = wave >> 1, wc = wave & 1;
    int m0 = blockIdx.x * 128 + wr * 64;
    int n0 = blockIdx.y * 128 + wc * 64;

    f32x4 acc[4][4];
    for (int a = 0; a < 4; a++)
        for (int b = 0; b < 4; b++)
            acc[a][b] = (f32x4){0.f, 0.f, 0.f, 0.f};

    const unsigned short* Abase = A + (size_t)(m0 + ln) * DMODEL + kq * 8;
    const unsigned short* Bbase = Wo + (size_t)(n0 + ln) * DMODEL + kq * 8;

    for (int k0 = 0; k0 < DMODEL; k0 += 32) {
        bf16x8 af[4], bfr[4];
#pragma unroll
        for (int mt = 0; mt < 4; mt++)
            af[mt] = *reinterpret_cast<const bf16x8*>(Abase + (size_t)mt * 16 * DMODEL + k0);
#pragma unroll
        for (int nt = 0; nt < 4; nt++)
            bfr[nt] = *reinterpret_cast<const bf16x8*>(Bbase + (size_t)nt * 16 * DMODEL + k0);
#pragma unroll
        for (int mt = 0; mt < 4; mt++)
#pragma unroll
            for (int nt = 0; nt < 4; nt++)
                acc[mt][nt] = __builtin_amdgcn_mfma_f32_16x16x32_bf16(af[mt], bfr[nt], acc[mt][nt], 0, 0, 0);
    }

#pragma unroll
    for (int mt = 0; mt < 4; mt++)
#pragma unroll
        for (int nt = 0; nt < 4; nt++)
#pragma unroll
            for (int j = 0; j < 4; j++) {
                int m = m0 + mt * 16 + kq * 4 + j;
                int n = n0 + nt * 16 + ln;
                out[(size_t)m * DMODEL + n] = acc[mt][nt][j];
            }
}

extern "C" void kernel_launch(void* const* d_in, const int* in_sizes, int n_in,
                              void* d_out, int out_size, void* d_ws, size_t ws_size,
                              hipStream_t stream) {
    const float* x  = (const float*)d_in[0];
    const int* tok  = (const int*)d_in[1];
    const float* wq = (const float*)d_in[2];
    const float* wk = (const float*)d_in[3];
    const float* wv = (const float*)d_in[4];
    const float* wo = (const float*)d_in[5];
    float* out = (float*)d_out;

    // workspace layout (bytes)
    const size_t XB_OFF = 0;               // 16,777,216
    const size_t WQ_OFF = 16777216;        // 2,097,152 each
    const size_t WK_OFF = 18874368;
    const size_t WV_OFF = 20971520;
    const size_t WO_OFF = 23068672;
    const size_t Q_OFF  = 25165824;        // 16,777,216 each
    const size_t K_OFF  = 41943040;
    const size_t VT_OFF = 58720256;
    const size_t O_OFF  = 75497472;
    const size_t CS_OFF = 92274688;        // 262,144 each
    const size_t SN_OFF = 92536832;
    const size_t WS_NEEDED = 92798976;
    if (ws_size < WS_NEEDED) return;  // not enough scratch; bail visibly

    char* ws = (char*)d_ws;
    unsigned short* Xb  = (unsigned short*)(ws + XB_OFF);
    unsigned short* Wqb = (unsigned short*)(ws + WQ_OFF);
    unsigned short* Wkb = (unsigned short*)(ws + WK_OFF);
    unsigned short* Wvb = (unsigned short*)(ws + WV_OFF);
    unsigned short* Wob = (unsigned short*)(ws + WO_OFF);
    unsigned short* Qb  = (unsigned short*)(ws + Q_OFF);
    unsigned short* Kb  = (unsigned short*)(ws + K_OFF);
    unsigned short* VTb = (unsigned short*)(ws + VT_OFF);
    unsigned short* Ob  = (unsigned short*)(ws + O_OFF);
    float* cs_tab = (float*)(ws + CS_OFF);
    float* sn_tab = (float*)(ws + SN_OFF);

    cvt_f32_bf16<<<8192, 256, 0, stream>>>(x,  Xb,  MROWS * DMODEL);
    cvt_f32_bf16<<<1024, 256, 0, stream>>>(wq, Wqb, DMODEL * DMODEL);
    cvt_f32_bf16<<<1024, 256, 0, stream>>>(wk, Wkb, DMODEL * DMODEL);
    cvt_f32_bf16<<<1024, 256, 0, stream>>>(wv, Wvb, DMODEL * DMODEL);
    cvt_f32_bf16<<<1024, 256, 0, stream>>>(wo, Wob, DMODEL * DMODEL);
    rope_table<<<256, 256, 0, stream>>>(tok, cs_tab, sn_tab);

    qkv_gemm<<<dim3(MROWS / 128, DMODEL / 128, 3), 256, 0, stream>>>(
        Xb, Wqb, Wkb, Wvb, cs_tab, sn_tab, Qb, Kb, VTb);

    attn_kernel<<<dim3(SLEN / 64, NHEADS, BATCH), 256, 0, stream>>>(Qb, Kb, VTb, Ob);

    out_gemm<<<dim3(MROWS / 128, DMODEL / 128, 1), 256, 0, stream>>>(Ob, Wob, out);
}

// Round 2
// 534.712 us; speedup vs baseline: 1.4275x; 1.4275x over previous
//
#include <hip/hip_runtime.h>

#define BATCH 4
#define SLEN 2048
#define DMODEL 1024
#define NHEADS 16
#define DK 64
#define MROWS (BATCH * SLEN)  // 8192

typedef short bf16x8 __attribute__((ext_vector_type(8)));
typedef unsigned short u16x4 __attribute__((ext_vector_type(4)));
typedef float f32x4 __attribute__((ext_vector_type(4)));

// ---- fp32 -> bf16 (round-to-nearest-even) ----
__device__ __forceinline__ unsigned short f2bf(float f) {
    unsigned u = __float_as_uint(f);
    unsigned r = u + 0x7FFFu + ((u >> 16) & 1u);
    return (unsigned short)(r >> 16);
}
__device__ __forceinline__ float bf2f(unsigned short b) {
    return __uint_as_float(((unsigned)b) << 16);
}

__device__ __forceinline__ void gload_lds16(const void* g, void* l) {
    __builtin_amdgcn_global_load_lds(
        (const __attribute__((address_space(1))) void*)g,
        (__attribute__((address_space(3))) void*)l, 16, 0, 0);
}

__global__ void cvt_f32_bf16(const float* __restrict__ in, unsigned short* __restrict__ out, int n) {
    int i = (blockIdx.x * blockDim.x + threadIdx.x) * 4;
    if (i >= n) return;
    float4 v = *reinterpret_cast<const float4*>(in + i);
    u16x4 o;
    o[0] = f2bf(v.x); o[1] = f2bf(v.y); o[2] = f2bf(v.z); o[3] = f2bf(v.w);
    *reinterpret_cast<u16x4*>(out + i) = o;
}

// ---- RoPE cos/sin table: [SLEN][32] each ----
__global__ void rope_table(const int* __restrict__ tok, float* __restrict__ cs, float* __restrict__ sn) {
    int idx = blockIdx.x * blockDim.x + threadIdx.x;
    if (idx >= SLEN * 32) return;
    int s = idx >> 5, fi = idx & 31;
    float invf = powf(10000.0f, -(float)(2 * fi) / 64.0f);
    float ang = (float)tok[s] * invf;
    cs[idx] = cosf(ang);
    sn[idx] = sinf(ang);
}

// ---- Fused QKV projection GEMM + RoPE epilogue (unchanged this round) ----
__global__ __launch_bounds__(256) void qkv_gemm(
    const unsigned short* __restrict__ X,
    const unsigned short* __restrict__ Wq,
    const unsigned short* __restrict__ Wk,
    const unsigned short* __restrict__ Wv,
    const float* __restrict__ cs_tab, const float* __restrict__ sn_tab,
    unsigned short* __restrict__ Q, unsigned short* __restrict__ K,
    unsigned short* __restrict__ VT)
{
    int tid = threadIdx.x, lane = tid & 63, wave = tid >> 6;
    int ln = lane & 15, kq = lane >> 4;
    int wr = wave >> 1, wc = wave & 1;
    int m0 = blockIdx.x * 128 + wr * 64;
    int n0 = blockIdx.y * 128 + wc * 64;
    int z = blockIdx.z;
    const unsigned short* W = (z == 0) ? Wq : (z == 1) ? Wk : Wv;

    f32x4 acc[4][4];
    for (int a = 0; a < 4; a++)
        for (int b = 0; b < 4; b++)
            acc[a][b] = (f32x4){0.f, 0.f, 0.f, 0.f};

    const unsigned short* Abase = X + (size_t)(m0 + ln) * DMODEL + kq * 8;
    const unsigned short* Bbase = W + (size_t)(n0 + ln) * DMODEL + kq * 8;

    for (int k0 = 0; k0 < DMODEL; k0 += 32) {
        bf16x8 af[4], bfr[4];
#pragma unroll
        for (int mt = 0; mt < 4; mt++)
            af[mt] = *reinterpret_cast<const bf16x8*>(Abase + (size_t)mt * 16 * DMODEL + k0);
#pragma unroll
        for (int nt = 0; nt < 4; nt++)
            bfr[nt] = *reinterpret_cast<const bf16x8*>(Bbase + (size_t)nt * 16 * DMODEL + k0);
#pragma unroll
        for (int mt = 0; mt < 4; mt++)
#pragma unroll
            for (int nt = 0; nt < 4; nt++)
                acc[mt][nt] = __builtin_amdgcn_mfma_f32_16x16x32_bf16(af[mt], bfr[nt], acc[mt][nt], 0, 0, 0);
    }

    bool isV = (z == 2);
    unsigned short* dstQK = (z == 0) ? Q : K;
#pragma unroll
    for (int nt = 0; nt < 4; nt++) {
        int n = n0 + nt * 16 + ln;
        int h = n >> 6, d = n & 63;
        int fi = d >> 1;
#pragma unroll
        for (int mt = 0; mt < 4; mt++) {
#pragma unroll
            for (int j = 0; j < 4; j++) {
                int m = m0 + mt * 16 + kq * 4 + j;
                int b = m >> 11, s = m & (SLEN - 1);
                float v = acc[mt][nt][j];
                if (!isV) {
                    float c = cs_tab[s * 32 + fi];
                    float si = sn_tab[s * 32 + fi];
                    float p = __shfl_xor(v, 1);
                    v = (d & 1) ? (p * si + v * c) : (v * c - p * si);
                    dstQK[(((size_t)(b * NHEADS + h) * SLEN + s) << 6) + d] = f2bf(v);
                } else {
                    VT[((size_t)(b * NHEADS + h) * DK + d) * SLEN + s] = f2bf(v);
                }
            }
        }
    }
}

// ---- Causal flash attention, v2 ----
// Block: 4 waves, 128 q-rows (32/wave). KV tiles of 64 staged in LDS
// (double-buffered, global_load_lds w16, XOR-swizzled source). One barrier/tile.
__global__ __launch_bounds__(256) void attn_kernel(
    const unsigned short* __restrict__ Q, const unsigned short* __restrict__ K,
    const unsigned short* __restrict__ VT, unsigned short* __restrict__ O)
{
    // K tile: 64 rows x 64 bf16 (8KB) as 512 slots of 16B; slot s=(r, cb) holds
    // global colblock cb^(r&7) of row r. Same for V (VT rows are dk).
    __shared__ alignas(16) unsigned short Kt[2][4096];
    __shared__ alignas(16) unsigned short Vt[2][4096];
    __shared__ alignas(16) unsigned short P_lds[4][32][72];  // pad 72 vs 64

    int tid = threadIdx.x, lane = tid & 63, wave = tid >> 6;
    int ln = lane & 15, kq = lane >> 4;
    int qb = blockIdx.x;
    int h = blockIdx.y, b = blockIdx.z;
    size_t headoff = ((size_t)b * NHEADS + h) * SLEN * DK;
    const unsigned short* Qh = Q + headoff;
    const unsigned short* Kh = K + headoff;
    const unsigned short* Vh = VT + headoff;  // [64][SLEN]
    int q0 = qb * 128 + wave * 32;

    // Q fragments: 2 m-tiles x 2 k-chunks
    bf16x8 aq[2][2];
#pragma unroll
    for (int mt = 0; mt < 2; mt++)
#pragma unroll
        for (int kc = 0; kc < 2; kc++)
            aq[mt][kc] = *reinterpret_cast<const bf16x8*>(
                Qh + (size_t)(q0 + mt * 16 + ln) * DK + kc * 32 + kq * 8);

    f32x4 oacc[2][4];
#pragma unroll
    for (int mt = 0; mt < 2; mt++)
#pragma unroll
        for (int nt = 0; nt < 4; nt++) oacc[mt][nt] = (f32x4){0.f, 0.f, 0.f, 0.f};
    float m_r[2][4], l_r[2][4];
#pragma unroll
    for (int mt = 0; mt < 2; mt++)
#pragma unroll
        for (int j = 0; j < 4; j++) { m_r[mt][j] = -1e30f; l_r[mt][j] = 0.f; }

    int tmax_w = (q0 + 31) >> 6;       // last tile this wave participates in
    int ntiles = 2 * qb + 2;           // block-wide tile count

    auto stage = [&](int buf, int t) {
        int kv0 = t << 6;
#pragma unroll
        for (int i = 0; i < 2; i++) {
            int s = i * 256 + tid;
            int r = s >> 3;
            int cb = (s & 7) ^ (r & 7);
            gload_lds16(Kh + (size_t)(kv0 + r) * DK + cb * 8,
                        &Kt[buf][(i * 256 + wave * 64) * 8]);
            gload_lds16(Vh + (size_t)r * SLEN + kv0 + cb * 8,
                        &Vt[buf][(i * 256 + wave * 64) * 8]);
        }
    };

    stage(0, 0);
    __syncthreads();  // compiler drains vmcnt before barrier

    for (int t = 0; t < ntiles; t++) {
        int buf = t & 1;
        if (t + 1 < ntiles) stage(buf ^ 1, t + 1);

        if (t <= tmax_w) {
            int kv0 = t << 6;
            // ---- QK^T from LDS ----
            f32x4 sacc[2][4];
#pragma unroll
            for (int mt = 0; mt < 2; mt++)
#pragma unroll
                for (int nt = 0; nt < 4; nt++) sacc[mt][nt] = (f32x4){0.f, 0.f, 0.f, 0.f};
#pragma unroll
            for (int nt = 0; nt < 4; nt++) {
                int rr = nt * 16 + ln;
#pragma unroll
                for (int kc = 0; kc < 2; kc++) {
                    int unit = (kc * 4 + kq) ^ (rr & 7);
                    bf16x8 bk = *reinterpret_cast<const bf16x8*>(&Kt[buf][rr * 64 + unit * 8]);
#pragma unroll
                    for (int mt = 0; mt < 2; mt++)
                        sacc[mt][nt] = __builtin_amdgcn_mfma_f32_16x16x32_bf16(aq[mt][kc], bk, sacc[mt][nt], 0, 0, 0);
                }
            }
            // ---- scale + causal mask ----
            bool doMask = (kv0 + 63 > q0);
#pragma unroll
            for (int mt = 0; mt < 2; mt++)
#pragma unroll
                for (int nt = 0; nt < 4; nt++)
#pragma unroll
                    for (int j = 0; j < 4; j++) {
                        float v = sacc[mt][nt][j] * 0.125f;
                        if (doMask) {
                            int col = kv0 + nt * 16 + ln;
                            int row = q0 + mt * 16 + kq * 4 + j;
                            if (col > row) v = -1e30f;
                        }
                        sacc[mt][nt][j] = v;
                    }
            // ---- online softmax (rows live on 16-lane groups) ----
            float mloc[2][4];
#pragma unroll
            for (int mt = 0; mt < 2; mt++)
#pragma unroll
                for (int j = 0; j < 4; j++)
                    mloc[mt][j] = fmaxf(fmaxf(sacc[mt][0][j], sacc[mt][1][j]),
                                        fmaxf(sacc[mt][2][j], sacc[mt][3][j]));
#pragma unroll
            for (int off = 1; off < 16; off <<= 1)
#pragma unroll
                for (int mt = 0; mt < 2; mt++)
#pragma unroll
                    for (int j = 0; j < 4; j++)
                        mloc[mt][j] = fmaxf(mloc[mt][j], __shfl_xor(mloc[mt][j], off));

            float so[2][4];
#pragma unroll
            for (int mt = 0; mt < 2; mt++)
#pragma unroll
                for (int j = 0; j < 4; j++) {
                    float mn = fmaxf(m_r[mt][j], mloc[mt][j]);
                    so[mt][j] = __expf(m_r[mt][j] - mn);
                    m_r[mt][j] = mn;
                }
            float rs[2][4] = {{0.f, 0.f, 0.f, 0.f}, {0.f, 0.f, 0.f, 0.f}};
#pragma unroll
            for (int mt = 0; mt < 2; mt++)
#pragma unroll
                for (int nt = 0; nt < 4; nt++)
#pragma unroll
                    for (int j = 0; j < 4; j++) {
                        float p = __expf(sacc[mt][nt][j] - m_r[mt][j]);
                        sacc[mt][nt][j] = p;
                        rs[mt][j] += p;
                    }
#pragma unroll
            for (int off = 1; off < 16; off <<= 1)
#pragma unroll
                for (int mt = 0; mt < 2; mt++)
#pragma unroll
                    for (int j = 0; j < 4; j++)
                        rs[mt][j] += __shfl_xor(rs[mt][j], off);
#pragma unroll
            for (int mt = 0; mt < 2; mt++)
#pragma unroll
                for (int j = 0; j < 4; j++) l_r[mt][j] = l_r[mt][j] * so[mt][j] + rs[mt][j];
#pragma unroll
            for (int mt = 0; mt < 2; mt++)
#pragma unroll
                for (int nt = 0; nt < 4; nt++)
#pragma unroll
                    for (int j = 0; j < 4; j++)
                        oacc[mt][nt][j] *= so[mt][j];

            // ---- P -> per-wave LDS (no block barrier needed) ----
#pragma unroll
            for (int mt = 0; mt < 2; mt++)
#pragma unroll
                for (int nt = 0; nt < 4; nt++)
#pragma unroll
                    for (int j = 0; j < 4; j++)
                        P_lds[wave][mt * 16 + kq * 4 + j][nt * 16 + ln] = f2bf(sacc[mt][nt][j]);
            asm volatile("s_waitcnt lgkmcnt(0)" ::: "memory");
            __builtin_amdgcn_sched_barrier(0);

            bf16x8 pa[2][2];
#pragma unroll
            for (int mt = 0; mt < 2; mt++)
#pragma unroll
                for (int kc = 0; kc < 2; kc++)
                    pa[mt][kc] = *reinterpret_cast<const bf16x8*>(&P_lds[wave][mt * 16 + ln][kc * 32 + kq * 8]);

            // ---- PV from LDS ----
#pragma unroll
            for (int nt = 0; nt < 4; nt++) {
                int rr = nt * 16 + ln;  // dk row in VT tile
#pragma unroll
                for (int kc = 0; kc < 2; kc++) {
                    int unit = (kc * 4 + kq) ^ (rr & 7);
                    bf16x8 bv = *reinterpret_cast<const bf16x8*>(&Vt[buf][rr * 64 + unit * 8]);
#pragma unroll
                    for (int mt = 0; mt < 2; mt++)
                        oacc[mt][nt] = __builtin_amdgcn_mfma_f32_16x16x32_bf16(pa[mt][kc], bv, oacc[mt][nt], 0, 0, 0);
                }
            }
        }
        __syncthreads();  // drains stage vmcnt + all LDS; next iter flips buffers
    }

    // epilogue: O[b][s][h*64+d] bf16
#pragma unroll
    for (int mt = 0; mt < 2; mt++)
#pragma unroll
        for (int nt = 0; nt < 4; nt++)
#pragma unroll
            for (int j = 0; j < 4; j++) {
                int row = q0 + mt * 16 + kq * 4 + j;
                float v = oacc[mt][nt][j] / l_r[mt][j];
                O[((size_t)b * SLEN + row) * DMODEL + h * 64 + nt * 16 + ln] = f2bf(v);
            }
}

// ---- Output projection: out = O @ Wo^T, fp32 result (unchanged) ----
__global__ __launch_bounds__(256) void out_gemm(
    const unsigned short* __restrict__ A, const unsigned short* __restrict__ Wo,
    float* __restrict__ out)
{
    int tid = threadIdx.x, lane = tid & 63, wave = tid >> 6;
    int ln = lane & 15, kq = lane >> 4;
    int wr = wave >> 1, wc = wave & 1;
    int m0 = blockIdx.x * 128 + wr * 64;
    int n0 = blockIdx.y * 128 + wc * 64;

    f32x4 acc[4][4];
    for (int a = 0; a < 4; a++)
        for (int b = 0; b < 4; b++)
            acc[a][b] = (f32x4){0.f, 0.f, 0.f, 0.f};

    const unsigned short* Abase = A + (size_t)(m0 + ln) * DMODEL + kq * 8;
    const unsigned short* Bbase = Wo + (size_t)(n0 + ln) * DMODEL + kq * 8;

    for (int k0 = 0; k0 < DMODEL; k0 += 32) {
        bf16x8 af[4], bfr[4];
#pragma unroll
        for (int mt = 0; mt < 4; mt++)
            af[mt] = *reinterpret_cast<const bf16x8*>(Abase + (size_t)mt * 16 * DMODEL + k0);
#pragma unroll
        for (int nt = 0; nt < 4; nt++)
            bfr[nt] = *reinterpret_cast<const bf16x8*>(Bbase + (size_t)nt * 16 * DMODEL + k0);
#pragma unroll
        for (int mt = 0; mt < 4; mt++)
#pragma unroll
            for (int nt = 0; nt < 4; nt++)
                acc[mt][nt] = __builtin_amdgcn_mfma_f32_16x16x32_bf16(af[mt], bfr[nt], acc[mt][nt], 0, 0, 0);
    }

#pragma unroll
    for (int mt = 0; mt < 4; mt++)
#pragma unroll
        for (int nt = 0; nt < 4; nt++)
#pragma unroll
            for (int j = 0; j < 4; j++) {
                int m = m0 + mt * 16 + kq * 4 + j;
                int n = n0 + nt * 16 + ln;
                out[(size_t)m * DMODEL + n] = acc[mt][nt][j];
            }
}

extern "C" void kernel_launch(void* const* d_in, const int* in_sizes, int n_in,
                              void* d_out, int out_size, void* d_ws, size_t ws_size,
                              hipStream_t stream) {
    const float* x  = (const float*)d_in[0];
    const int* tok  = (const int*)d_in[1];
    const float* wq = (const float*)d_in[2];
    const float* wk = (const float*)d_in[3];
    const float* wv = (const float*)d_in[4];
    const float* wo = (const float*)d_in[5];
    float* out = (float*)d_out;

    const size_t XB_OFF = 0;
    const size_t WQ_OFF = 16777216;
    const size_t WK_OFF = 18874368;
    const size_t WV_OFF = 20971520;
    const size_t WO_OFF = 23068672;
    const size_t Q_OFF  = 25165824;
    const size_t K_OFF  = 41943040;
    const size_t VT_OFF = 58720256;
    const size_t O_OFF  = 75497472;
    const size_t CS_OFF = 92274688;
    const size_t SN_OFF = 92536832;
    const size_t WS_NEEDED = 92798976;
    if (ws_size < WS_NEEDED) return;

    char* ws = (char*)d_ws;
    unsigned short* Xb  = (unsigned short*)(ws + XB_OFF);
    unsigned short* Wqb = (unsigned short*)(ws + WQ_OFF);
    unsigned short* Wkb = (unsigned short*)(ws + WK_OFF);
    unsigned short* Wvb = (unsigned short*)(ws + WV_OFF);
    unsigned short* Wob = (unsigned short*)(ws + WO_OFF);
    unsigned short* Qb  = (unsigned short*)(ws + Q_OFF);
    unsigned short* Kb  = (unsigned short*)(ws + K_OFF);
    unsigned short* VTb = (unsigned short*)(ws + VT_OFF);
    unsigned short* Ob  = (unsigned short*)(ws + O_OFF);
    float* cs_tab = (float*)(ws + CS_OFF);
    float* sn_tab = (float*)(ws + SN_OFF);

    cvt_f32_bf16<<<8192, 256, 0, stream>>>(x,  Xb,  MROWS * DMODEL);
    cvt_f32_bf16<<<1024, 256, 0, stream>>>(wq, Wqb, DMODEL * DMODEL);
    cvt_f32_bf16<<<1024, 256, 0, stream>>>(wk, Wkb, DMODEL * DMODEL);
    cvt_f32_bf16<<<1024, 256, 0, stream>>>(wv, Wvb, DMODEL * DMODEL);
    cvt_f32_bf16<<<1024, 256, 0, stream>>>(wo, Wob, DMODEL * DMODEL);
    rope_table<<<256, 256, 0, stream>>>(tok, cs_tab, sn_tab);

    qkv_gemm<<<dim3(MROWS / 128, DMODEL / 128, 3), 256, 0, stream>>>(
        Xb, Wqb, Wkb, Wvb, cs_tab, sn_tab, Qb, Kb, VTb);

    attn_kernel<<<dim3(SLEN / 128, NHEADS, BATCH), 256, 0, stream>>>(Qb, Kb, VTb, Ob);

    out_gemm<<<dim3(MROWS / 128, DMODEL / 128, 1), 256, 0, stream>>>(Ob, Wob, out);
}

// Round 3
// 263.850 us; speedup vs baseline: 2.8930x; 2.0266x over previous
//
#include <hip/hip_runtime.h>

#define BATCH 4
#define SLEN 2048
#define DMODEL 1024
#define NHEADS 16
#define DK 64
#define MROWS (BATCH * SLEN)  // 8192
#define NQB 16                // SLEN/128 q-strips

typedef short bf16x8 __attribute__((ext_vector_type(8)));
typedef unsigned short u16x4 __attribute__((ext_vector_type(4)));
typedef float f32x4 __attribute__((ext_vector_type(4)));

__device__ __forceinline__ unsigned short f2bf(float f) {
    unsigned u = __float_as_uint(f);
    unsigned r = u + 0x7FFFu + ((u >> 16) & 1u);
    return (unsigned short)(r >> 16);
}
__device__ __forceinline__ float bf2f(unsigned short b) {
    return __uint_as_float(((unsigned)b) << 16);
}

__device__ __forceinline__ void gload_lds16(const void* g, void* l) {
    __builtin_amdgcn_global_load_lds(
        (const __attribute__((address_space(1))) void*)g,
        (__attribute__((address_space(3))) void*)l, 16, 0, 0);
}

__global__ void cvt_f32_bf16(const float* __restrict__ in, unsigned short* __restrict__ out, int n) {
    int i = (blockIdx.x * blockDim.x + threadIdx.x) * 4;
    if (i >= n) return;
    float4 v = *reinterpret_cast<const float4*>(in + i);
    u16x4 o;
    o[0] = f2bf(v.x); o[1] = f2bf(v.y); o[2] = f2bf(v.z); o[3] = f2bf(v.w);
    *reinterpret_cast<u16x4*>(out + i) = o;
}

__global__ void rope_table(const int* __restrict__ tok, float* __restrict__ cs, float* __restrict__ sn) {
    int idx = blockIdx.x * blockDim.x + threadIdx.x;
    if (idx >= SLEN * 32) return;
    int s = idx >> 5, fi = idx & 31;
    float invf = powf(10000.0f, -(float)(2 * fi) / 64.0f);
    float ang = (float)tok[s] * invf;
    cs[idx] = cosf(ang);
    sn[idx] = sinf(ang);
}

// ---- m97-style 128x128 GEMM core: LDS-staged via global_load_lds w16,
// XOR-swizzled source + swizzled ds_read (both-sides). 2 barriers / K-step. ----
__device__ __forceinline__ void gemm128_core(
    const unsigned short* __restrict__ A, const unsigned short* __restrict__ B,
    int m0, int n0, int tid, f32x4 (&acc)[4][4],
    unsigned short* As, unsigned short* Bs)
{
    int lane = tid & 63, wave = tid >> 6;
    int ln = lane & 15, kq = lane >> 4;
    int wr = wave >> 1, wc = wave & 1;
#pragma unroll
    for (int a = 0; a < 4; a++)
#pragma unroll
        for (int b = 0; b < 4; b++) acc[a][b] = (f32x4){0.f, 0.f, 0.f, 0.f};

    for (int k0 = 0; k0 < DMODEL; k0 += 64) {
        if (k0) __syncthreads();
        // stage A,B tiles: 128 rows x 64 cols bf16, 1024 slots of 16B each
#pragma unroll
        for (int i = 0; i < 4; i++) {
            int s = i * 256 + tid;
            int r = s >> 3;
            int u = (s & 7) ^ (r & 7);  // pre-swizzled global source
            gload_lds16(A + (size_t)(m0 + r) * DMODEL + k0 + u * 8, &As[(i * 256 + wave * 64) * 8]);
            gload_lds16(B + (size_t)(n0 + r) * DMODEL + k0 + u * 8, &Bs[(i * 256 + wave * 64) * 8]);
        }
        __syncthreads();

        bf16x8 af[4][2], bfr[4][2];
#pragma unroll
        for (int mt = 0; mt < 4; mt++) {
            int row = wr * 64 + mt * 16 + ln;
#pragma unroll
            for (int kc = 0; kc < 2; kc++) {
                int u = (kc * 4 + kq) ^ (row & 7);
                af[mt][kc] = *reinterpret_cast<const bf16x8*>(&As[row * 64 + u * 8]);
            }
        }
#pragma unroll
        for (int nt = 0; nt < 4; nt++) {
            int row = wc * 64 + nt * 16 + ln;
#pragma unroll
            for (int kc = 0; kc < 2; kc++) {
                int u = (kc * 4 + kq) ^ (row & 7);
                bfr[nt][kc] = *reinterpret_cast<const bf16x8*>(&Bs[row * 64 + u * 8]);
            }
        }
        __builtin_amdgcn_s_setprio(1);
#pragma unroll
        for (int kc = 0; kc < 2; kc++)
#pragma unroll
            for (int mt = 0; mt < 4; mt++)
#pragma unroll
                for (int nt = 0; nt < 4; nt++)
                    acc[mt][nt] = __builtin_amdgcn_mfma_f32_16x16x32_bf16(af[mt][kc], bfr[nt][kc], acc[mt][nt], 0, 0, 0);
        __builtin_amdgcn_s_setprio(0);
    }
}

// ---- Fused QKV projection GEMM + RoPE epilogue ----
__global__ __launch_bounds__(256) void qkv_gemm(
    const unsigned short* __restrict__ X,
    const unsigned short* __restrict__ Wq,
    const unsigned short* __restrict__ Wk,
    const unsigned short* __restrict__ Wv,
    const float* __restrict__ cs_tab, const float* __restrict__ sn_tab,
    unsigned short* __restrict__ Q, unsigned short* __restrict__ K,
    unsigned short* __restrict__ VT)
{
    __shared__ alignas(16) unsigned short As[128 * 64];
    __shared__ alignas(16) unsigned short Bs[128 * 64];
    int tid = threadIdx.x, lane = tid & 63, wave = tid >> 6;
    int ln = lane & 15, kq = lane >> 4;
    int wr = wave >> 1, wc = wave & 1;
    int m0 = blockIdx.x * 128;
    int n0 = blockIdx.y * 128;
    int z = blockIdx.z;
    const unsigned short* W = (z == 0) ? Wq : (z == 1) ? Wk : Wv;

    f32x4 acc[4][4];
    gemm128_core(X, W, m0, n0, tid, acc, As, Bs);

    bool isV = (z == 2);
    unsigned short* dstQK = (z == 0) ? Q : K;
    int m0w = m0 + wr * 64, n0w = n0 + wc * 64;
#pragma unroll
    for (int nt = 0; nt < 4; nt++) {
        int n = n0w + nt * 16 + ln;
        int h = n >> 6, d = n & 63;
        int fi = d >> 1;
#pragma unroll
        for (int mt = 0; mt < 4; mt++) {
#pragma unroll
            for (int j = 0; j < 4; j++) {
                int m = m0w + mt * 16 + kq * 4 + j;
                int b = m >> 11, s = m & (SLEN - 1);
                float v = acc[mt][nt][j];
                if (!isV) {
                    float c = cs_tab[s * 32 + fi];
                    float si = sn_tab[s * 32 + fi];
                    float p = __shfl_xor(v, 1);
                    v = (d & 1) ? (p * si + v * c) : (v * c - p * si);
                    dstQK[(((size_t)(b * NHEADS + h) * SLEN + s) << 6) + d] = f2bf(v);
                } else {
                    VT[((size_t)(b * NHEADS + h) * DK + d) * SLEN + s] = f2bf(v);
                }
            }
        }
    }
}

// ---- Causal flash attention v3: paired q-strips for uniform work ----
// Block: 4 waves, two 128-row q-strips (15-qb then qb) -> 34 tiles/block uniform.
__global__ __launch_bounds__(256) void attn_kernel(
    const unsigned short* __restrict__ Q, const unsigned short* __restrict__ K,
    const unsigned short* __restrict__ VT, unsigned short* __restrict__ O)
{
    __shared__ alignas(16) unsigned short Kt[2][4096];
    __shared__ alignas(16) unsigned short Vt[2][4096];
    __shared__ alignas(16) unsigned short P_lds[4][32][72];

    int tid = threadIdx.x, lane = tid & 63, wave = tid >> 6;
    int ln = lane & 15, kq = lane >> 4;
    int qb = blockIdx.x;  // 0..7
    int h = blockIdx.y, b = blockIdx.z;
    size_t headoff = ((size_t)b * NHEADS + h) * SLEN * DK;
    const unsigned short* Qh = Q + headoff;
    const unsigned short* Kh = K + headoff;
    const unsigned short* Vh = VT + headoff;  // [64][SLEN]

    auto stage = [&](int buf, int t) {
        int kv0 = t << 6;
#pragma unroll
        for (int i = 0; i < 2; i++) {
            int s = i * 256 + tid;
            int r = s >> 3;
            int cb = (s & 7) ^ (r & 7);
            gload_lds16(Kh + (size_t)(kv0 + r) * DK + cb * 8,
                        &Kt[buf][(i * 256 + wave * 64) * 8]);
            gload_lds16(Vh + (size_t)r * SLEN + kv0 + cb * 8,
                        &Vt[buf][(i * 256 + wave * 64) * 8]);
        }
    };

    for (int sid = 0; sid < 2; sid++) {
        int qs = sid ? qb : (NQB - 1 - qb);
        int q0 = qs * 128 + wave * 32;

        bf16x8 aq[2][2];
#pragma unroll
        for (int mt = 0; mt < 2; mt++)
#pragma unroll
            for (int kc = 0; kc < 2; kc++)
                aq[mt][kc] = *reinterpret_cast<const bf16x8*>(
                    Qh + (size_t)(q0 + mt * 16 + ln) * DK + kc * 32 + kq * 8);

        f32x4 oacc[2][4];
#pragma unroll
        for (int mt = 0; mt < 2; mt++)
#pragma unroll
            for (int nt = 0; nt < 4; nt++) oacc[mt][nt] = (f32x4){0.f, 0.f, 0.f, 0.f};
        float m_r[2][4], l_r[2][4];
#pragma unroll
        for (int mt = 0; mt < 2; mt++)
#pragma unroll
            for (int j = 0; j < 4; j++) { m_r[mt][j] = -1e30f; l_r[mt][j] = 0.f; }

        int tmax_w = (q0 + 31) >> 6;
        int ntiles = 2 * qs + 2;

        stage(0, 0);
        __syncthreads();

        for (int t = 0; t < ntiles; t++) {
            int buf = t & 1;
            if (t + 1 < ntiles) stage(buf ^ 1, t + 1);

            if (t <= tmax_w) {
                int kv0 = t << 6;
                f32x4 sacc[2][4];
#pragma unroll
                for (int mt = 0; mt < 2; mt++)
#pragma unroll
                    for (int nt = 0; nt < 4; nt++) sacc[mt][nt] = (f32x4){0.f, 0.f, 0.f, 0.f};
                __builtin_amdgcn_s_setprio(1);
#pragma unroll
                for (int nt = 0; nt < 4; nt++) {
                    int rr = nt * 16 + ln;
#pragma unroll
                    for (int kc = 0; kc < 2; kc++) {
                        int unit = (kc * 4 + kq) ^ (rr & 7);
                        bf16x8 bk = *reinterpret_cast<const bf16x8*>(&Kt[buf][rr * 64 + unit * 8]);
#pragma unroll
                        for (int mt = 0; mt < 2; mt++)
                            sacc[mt][nt] = __builtin_amdgcn_mfma_f32_16x16x32_bf16(aq[mt][kc], bk, sacc[mt][nt], 0, 0, 0);
                    }
                }
                __builtin_amdgcn_s_setprio(0);

                bool doMask = (kv0 + 63 > q0);
#pragma unroll
                for (int mt = 0; mt < 2; mt++)
#pragma unroll
                    for (int nt = 0; nt < 4; nt++)
#pragma unroll
                        for (int j = 0; j < 4; j++) {
                            float v = sacc[mt][nt][j] * 0.125f;
                            if (doMask) {
                                int col = kv0 + nt * 16 + ln;
                                int row = q0 + mt * 16 + kq * 4 + j;
                                if (col > row) v = -1e30f;
                            }
                            sacc[mt][nt][j] = v;
                        }
                float mloc[2][4];
#pragma unroll
                for (int mt = 0; mt < 2; mt++)
#pragma unroll
                    for (int j = 0; j < 4; j++)
                        mloc[mt][j] = fmaxf(fmaxf(sacc[mt][0][j], sacc[mt][1][j]),
                                            fmaxf(sacc[mt][2][j], sacc[mt][3][j]));
#pragma unroll
                for (int off = 1; off < 16; off <<= 1)
#pragma unroll
                    for (int mt = 0; mt < 2; mt++)
#pragma unroll
                        for (int j = 0; j < 4; j++)
                            mloc[mt][j] = fmaxf(mloc[mt][j], __shfl_xor(mloc[mt][j], off));

                float so[2][4];
#pragma unroll
                for (int mt = 0; mt < 2; mt++)
#pragma unroll
                    for (int j = 0; j < 4; j++) {
                        float mn = fmaxf(m_r[mt][j], mloc[mt][j]);
                        so[mt][j] = __expf(m_r[mt][j] - mn);
                        m_r[mt][j] = mn;
                    }
                float rs[2][4] = {{0.f, 0.f, 0.f, 0.f}, {0.f, 0.f, 0.f, 0.f}};
#pragma unroll
                for (int mt = 0; mt < 2; mt++)
#pragma unroll
                    for (int nt = 0; nt < 4; nt++)
#pragma unroll
                        for (int j = 0; j < 4; j++) {
                            float p = __expf(sacc[mt][nt][j] - m_r[mt][j]);
                            sacc[mt][nt][j] = p;
                            rs[mt][j] += p;
                        }
#pragma unroll
                for (int off = 1; off < 16; off <<= 1)
#pragma unroll
                    for (int mt = 0; mt < 2; mt++)
#pragma unroll
                        for (int j = 0; j < 4; j++)
                            rs[mt][j] += __shfl_xor(rs[mt][j], off);
#pragma unroll
                for (int mt = 0; mt < 2; mt++)
#pragma unroll
                    for (int j = 0; j < 4; j++) l_r[mt][j] = l_r[mt][j] * so[mt][j] + rs[mt][j];
#pragma unroll
                for (int mt = 0; mt < 2; mt++)
#pragma unroll
                    for (int nt = 0; nt < 4; nt++)
#pragma unroll
                        for (int j = 0; j < 4; j++)
                            oacc[mt][nt][j] *= so[mt][j];

#pragma unroll
                for (int mt = 0; mt < 2; mt++)
#pragma unroll
                    for (int nt = 0; nt < 4; nt++)
#pragma unroll
                        for (int j = 0; j < 4; j++)
                            P_lds[wave][mt * 16 + kq * 4 + j][nt * 16 + ln] = f2bf(sacc[mt][nt][j]);
                asm volatile("s_waitcnt lgkmcnt(0)" ::: "memory");
                __builtin_amdgcn_sched_barrier(0);

                bf16x8 pa[2][2];
#pragma unroll
                for (int mt = 0; mt < 2; mt++)
#pragma unroll
                    for (int kc = 0; kc < 2; kc++)
                        pa[mt][kc] = *reinterpret_cast<const bf16x8*>(&P_lds[wave][mt * 16 + ln][kc * 32 + kq * 8]);

                __builtin_amdgcn_s_setprio(1);
#pragma unroll
                for (int nt = 0; nt < 4; nt++) {
                    int rr = nt * 16 + ln;
#pragma unroll
                    for (int kc = 0; kc < 2; kc++) {
                        int unit = (kc * 4 + kq) ^ (rr & 7);
                        bf16x8 bv = *reinterpret_cast<const bf16x8*>(&Vt[buf][rr * 64 + unit * 8]);
#pragma unroll
                        for (int mt = 0; mt < 2; mt++)
                            oacc[mt][nt] = __builtin_amdgcn_mfma_f32_16x16x32_bf16(pa[mt][kc], bv, oacc[mt][nt], 0, 0, 0);
                    }
                }
                __builtin_amdgcn_s_setprio(0);
            }
            __syncthreads();
        }

#pragma unroll
        for (int mt = 0; mt < 2; mt++)
#pragma unroll
            for (int nt = 0; nt < 4; nt++)
#pragma unroll
                for (int j = 0; j < 4; j++) {
                    int row = q0 + mt * 16 + kq * 4 + j;
                    float v = oacc[mt][nt][j] / l_r[mt][j];
                    O[((size_t)b * SLEN + row) * DMODEL + h * 64 + nt * 16 + ln] = f2bf(v);
                }
        __syncthreads();  // strip B restages buf0 next
    }
}

// ---- Output projection: out = O @ Wo^T, fp32 result ----
__global__ __launch_bounds__(256) void out_gemm(
    const unsigned short* __restrict__ A, const unsigned short* __restrict__ Wo,
    float* __restrict__ out)
{
    __shared__ alignas(16) unsigned short As[128 * 64];
    __shared__ alignas(16) unsigned short Bs[128 * 64];
    int tid = threadIdx.x, lane = tid & 63, wave = tid >> 6;
    int ln = lane & 15, kq = lane >> 4;
    int wr = wave >> 1, wc = wave & 1;
    int m0 = blockIdx.x * 128;
    int n0 = blockIdx.y * 128;

    f32x4 acc[4][4];
    gemm128_core(A, Wo, m0, n0, tid, acc, As, Bs);

    int m0w = m0 + wr * 64, n0w = n0 + wc * 64;
#pragma unroll
    for (int mt = 0; mt < 4; mt++)
#pragma unroll
        for (int nt = 0; nt < 4; nt++)
#pragma unroll
            for (int j = 0; j < 4; j++) {
                int m = m0w + mt * 16 + kq * 4 + j;
                int n = n0w + nt * 16 + ln;
                out[(size_t)m * DMODEL + n] = acc[mt][nt][j];
            }
}

extern "C" void kernel_launch(void* const* d_in, const int* in_sizes, int n_in,
                              void* d_out, int out_size, void* d_ws, size_t ws_size,
                              hipStream_t stream) {
    const float* x  = (const float*)d_in[0];
    const int* tok  = (const int*)d_in[1];
    const float* wq = (const float*)d_in[2];
    const float* wk = (const float*)d_in[3];
    const float* wv = (const float*)d_in[4];
    const float* wo = (const float*)d_in[5];
    float* out = (float*)d_out;

    const size_t XB_OFF = 0;
    const size_t WQ_OFF = 16777216;
    const size_t WK_OFF = 18874368;
    const size_t WV_OFF = 20971520;
    const size_t WO_OFF = 23068672;
    const size_t Q_OFF  = 25165824;
    const size_t K_OFF  = 41943040;
    const size_t VT_OFF = 58720256;
    const size_t O_OFF  = 75497472;
    const size_t CS_OFF = 92274688;
    const size_t SN_OFF = 92536832;
    const size_t WS_NEEDED = 92798976;
    if (ws_size < WS_NEEDED) return;

    char* ws = (char*)d_ws;
    unsigned short* Xb  = (unsigned short*)(ws + XB_OFF);
    unsigned short* Wqb = (unsigned short*)(ws + WQ_OFF);
    unsigned short* Wkb = (unsigned short*)(ws + WK_OFF);
    unsigned short* Wvb = (unsigned short*)(ws + WV_OFF);
    unsigned short* Wob = (unsigned short*)(ws + WO_OFF);
    unsigned short* Qb  = (unsigned short*)(ws + Q_OFF);
    unsigned short* Kb  = (unsigned short*)(ws + K_OFF);
    unsigned short* VTb = (unsigned short*)(ws + VT_OFF);
    unsigned short* Ob  = (unsigned short*)(ws + O_OFF);
    float* cs_tab = (float*)(ws + CS_OFF);
    float* sn_tab = (float*)(ws + SN_OFF);

    cvt_f32_bf16<<<8192, 256, 0, stream>>>(x,  Xb,  MROWS * DMODEL);
    cvt_f32_bf16<<<1024, 256, 0, stream>>>(wq, Wqb, DMODEL * DMODEL);
    cvt_f32_bf16<<<1024, 256, 0, stream>>>(wk, Wkb, DMODEL * DMODEL);
    cvt_f32_bf16<<<1024, 256, 0, stream>>>(wv, Wvb, DMODEL * DMODEL);
    cvt_f32_bf16<<<1024, 256, 0, stream>>>(wo, Wob, DMODEL * DMODEL);
    rope_table<<<256, 256, 0, stream>>>(tok, cs_tab, sn_tab);

    qkv_gemm<<<dim3(MROWS / 128, DMODEL / 128, 3), 256, 0, stream>>>(
        Xb, Wqb, Wkb, Wvb, cs_tab, sn_tab, Qb, Kb, VTb);

    attn_kernel<<<dim3(SLEN / 256, NHEADS, BATCH), 256, 0, stream>>>(Qb, Kb, VTb, Ob);

    out_gemm<<<dim3(MROWS / 128, DMODEL / 128, 1), 256, 0, stream>>>(Ob, Wob, out);
}

// Round 4
// 231.231 us; speedup vs baseline: 3.3012x; 1.1411x over previous
//
#include <hip/hip_runtime.h>

#define BATCH 4
#define SLEN 2048
#define DMODEL 1024
#define NHEADS 16
#define DK 64
#define MROWS (BATCH * SLEN)  // 8192
#define NQB 16                // SLEN/128 q-strips
#define SCALE_LOG2E 0.1803368801111731f  // 0.125 * log2(e), folded into Q

typedef short bf16x8 __attribute__((ext_vector_type(8)));
typedef unsigned short u16x4 __attribute__((ext_vector_type(4)));
typedef float f32x4 __attribute__((ext_vector_type(4)));

__device__ __forceinline__ unsigned short f2bf(float f) {
    unsigned u = __float_as_uint(f);
    unsigned r = u + 0x7FFFu + ((u >> 16) & 1u);
    return (unsigned short)(r >> 16);
}

__device__ __forceinline__ void gload_lds16(const void* g, void* l) {
    __builtin_amdgcn_global_load_lds(
        (const __attribute__((address_space(1))) void*)g,
        (__attribute__((address_space(3))) void*)l, 16, 0, 0);
}

__global__ void cvt_f32_bf16(const float* __restrict__ in, unsigned short* __restrict__ out, int n) {
    int i = (blockIdx.x * blockDim.x + threadIdx.x) * 4;
    if (i >= n) return;
    float4 v = *reinterpret_cast<const float4*>(in + i);
    u16x4 o;
    o[0] = f2bf(v.x); o[1] = f2bf(v.y); o[2] = f2bf(v.z); o[3] = f2bf(v.w);
    *reinterpret_cast<u16x4*>(out + i) = o;
}

__global__ void rope_table(const int* __restrict__ tok, float* __restrict__ cs, float* __restrict__ sn) {
    int idx = blockIdx.x * blockDim.x + threadIdx.x;
    if (idx >= SLEN * 32) return;
    int s = idx >> 5, fi = idx & 31;
    float invf = powf(10000.0f, -(float)(2 * fi) / 64.0f);
    float ang = (float)tok[s] * invf;
    cs[idx] = cosf(ang);
    sn[idx] = sinf(ang);
}

// ---- m97-style 128x128 GEMM core ----
__device__ __forceinline__ void gemm128_core(
    const unsigned short* __restrict__ A, const unsigned short* __restrict__ B,
    int m0, int n0, int tid, f32x4 (&acc)[4][4],
    unsigned short* As, unsigned short* Bs)
{
    int lane = tid & 63, wave = tid >> 6;
    int ln = lane & 15, kq = lane >> 4;
    int wr = wave >> 1, wc = wave & 1;
#pragma unroll
    for (int a = 0; a < 4; a++)
#pragma unroll
        for (int b = 0; b < 4; b++) acc[a][b] = (f32x4){0.f, 0.f, 0.f, 0.f};

    for (int k0 = 0; k0 < DMODEL; k0 += 64) {
        if (k0) __syncthreads();
#pragma unroll
        for (int i = 0; i < 4; i++) {
            int s = i * 256 + tid;
            int r = s >> 3;
            int u = (s & 7) ^ (r & 7);
            gload_lds16(A + (size_t)(m0 + r) * DMODEL + k0 + u * 8, &As[(i * 256 + wave * 64) * 8]);
            gload_lds16(B + (size_t)(n0 + r) * DMODEL + k0 + u * 8, &Bs[(i * 256 + wave * 64) * 8]);
        }
        __syncthreads();

        bf16x8 af[4][2], bfr[4][2];
#pragma unroll
        for (int mt = 0; mt < 4; mt++) {
            int row = wr * 64 + mt * 16 + ln;
#pragma unroll
            for (int kc = 0; kc < 2; kc++) {
                int u = (kc * 4 + kq) ^ (row & 7);
                af[mt][kc] = *reinterpret_cast<const bf16x8*>(&As[row * 64 + u * 8]);
            }
        }
#pragma unroll
        for (int nt = 0; nt < 4; nt++) {
            int row = wc * 64 + nt * 16 + ln;
#pragma unroll
            for (int kc = 0; kc < 2; kc++) {
                int u = (kc * 4 + kq) ^ (row & 7);
                bfr[nt][kc] = *reinterpret_cast<const bf16x8*>(&Bs[row * 64 + u * 8]);
            }
        }
        __builtin_amdgcn_s_setprio(1);
#pragma unroll
        for (int kc = 0; kc < 2; kc++)
#pragma unroll
            for (int mt = 0; mt < 4; mt++)
#pragma unroll
                for (int nt = 0; nt < 4; nt++)
                    acc[mt][nt] = __builtin_amdgcn_mfma_f32_16x16x32_bf16(af[mt][kc], bfr[nt][kc], acc[mt][nt], 0, 0, 0);
        __builtin_amdgcn_s_setprio(0);
    }
}

// ---- Fused QKV projection GEMM + RoPE epilogue; Q pre-scaled by 0.125*log2e ----
__global__ __launch_bounds__(256) void qkv_gemm(
    const unsigned short* __restrict__ X,
    const unsigned short* __restrict__ Wq,
    const unsigned short* __restrict__ Wk,
    const unsigned short* __restrict__ Wv,
    const float* __restrict__ cs_tab, const float* __restrict__ sn_tab,
    unsigned short* __restrict__ Q, unsigned short* __restrict__ K,
    unsigned short* __restrict__ VT)
{
    __shared__ alignas(16) unsigned short As[128 * 64];
    __shared__ alignas(16) unsigned short Bs[128 * 64];
    int tid = threadIdx.x, lane = tid & 63, wave = tid >> 6;
    int ln = lane & 15, kq = lane >> 4;
    int wr = wave >> 1, wc = wave & 1;
    int m0 = blockIdx.x * 128;
    int n0 = blockIdx.y * 128;
    int z = blockIdx.z;
    const unsigned short* W = (z == 0) ? Wq : (z == 1) ? Wk : Wv;

    f32x4 acc[4][4];
    gemm128_core(X, W, m0, n0, tid, acc, As, Bs);

    bool isV = (z == 2);
    bool isQ = (z == 0);
    unsigned short* dstQK = (z == 0) ? Q : K;
    int m0w = m0 + wr * 64, n0w = n0 + wc * 64;
#pragma unroll
    for (int nt = 0; nt < 4; nt++) {
        int n = n0w + nt * 16 + ln;
        int h = n >> 6, d = n & 63;
        int fi = d >> 1;
#pragma unroll
        for (int mt = 0; mt < 4; mt++) {
#pragma unroll
            for (int j = 0; j < 4; j++) {
                int m = m0w + mt * 16 + kq * 4 + j;
                int b = m >> 11, s = m & (SLEN - 1);
                float v = acc[mt][nt][j];
                if (!isV) {
                    float c = cs_tab[s * 32 + fi];
                    float si = sn_tab[s * 32 + fi];
                    float p = __shfl_xor(v, 1);
                    v = (d & 1) ? (p * si + v * c) : (v * c - p * si);
                    if (isQ) v *= SCALE_LOG2E;
                    dstQK[(((size_t)(b * NHEADS + h) * SLEN + s) << 6) + d] = f2bf(v);
                } else {
                    VT[((size_t)(b * NHEADS + h) * DK + d) * SLEN + s] = f2bf(v);
                }
            }
        }
    }
}

// ---- Causal flash attention v4: swapped QK^T (S^T in regs, q lane-local) ----
// Block: 4 waves, paired q-strips (15-qb, qb). KV tiles of 64 double-buffered.
__global__ __launch_bounds__(256) void attn_kernel(
    const unsigned short* __restrict__ Q, const unsigned short* __restrict__ K,
    const unsigned short* __restrict__ VT, unsigned short* __restrict__ O)
{
    __shared__ alignas(16) unsigned short Kt[2][4096];
    __shared__ alignas(16) unsigned short Vt[2][4096];
    __shared__ alignas(16) unsigned short P_lds[4][32][72];  // [q][k], stride 72

    int tid = threadIdx.x, lane = tid & 63, wave = tid >> 6;
    int ln = lane & 15, kq = lane >> 4;
    int qb = blockIdx.x;  // 0..7
    int h = blockIdx.y, b = blockIdx.z;
    size_t headoff = ((size_t)b * NHEADS + h) * SLEN * DK;
    const unsigned short* Qh = Q + headoff;
    const unsigned short* Kh = K + headoff;
    const unsigned short* Vh = VT + headoff;  // [64][SLEN]

    auto stage = [&](int buf, int t) {
        int kv0 = t << 6;
#pragma unroll
        for (int i = 0; i < 2; i++) {
            int s = i * 256 + tid;
            int r = s >> 3;
            int cb = (s & 7) ^ (r & 7);
            gload_lds16(Kh + (size_t)(kv0 + r) * DK + cb * 8,
                        &Kt[buf][(i * 256 + wave * 64) * 8]);
            gload_lds16(Vh + (size_t)r * SLEN + kv0 + cb * 8,
                        &Vt[buf][(i * 256 + wave * 64) * 8]);
        }
    };

    for (int sid = 0; sid < 2; sid++) {
        int qs = sid ? qb : (NQB - 1 - qb);
        int q0 = qs * 128 + wave * 32;

        bf16x8 aq[2][2];
#pragma unroll
        for (int mt = 0; mt < 2; mt++)
#pragma unroll
            for (int kc = 0; kc < 2; kc++)
                aq[mt][kc] = *reinterpret_cast<const bf16x8*>(
                    Qh + (size_t)(q0 + mt * 16 + ln) * DK + kc * 32 + kq * 8);

        f32x4 oacc[2][4];
#pragma unroll
        for (int mt = 0; mt < 2; mt++)
#pragma unroll
            for (int nt = 0; nt < 4; nt++) oacc[mt][nt] = (f32x4){0.f, 0.f, 0.f, 0.f};
        float m_r[2] = {-1e30f, -1e30f};
        float l_r[2] = {0.f, 0.f};

        int tmax_w = (q0 + 31) >> 6;
        int ntiles = 2 * qs + 2;

        stage(0, 0);
        __syncthreads();

        for (int t = 0; t < ntiles; t++) {
            int buf = t & 1;
            if (t + 1 < ntiles) stage(buf ^ 1, t + 1);

            if (t <= tmax_w) {
                int kv0 = t << 6;
                // ---- QK^T swapped: sacc = S^T; col(ln)=q, row(kq*4+j)=k ----
                f32x4 sacc[2][4];
#pragma unroll
                for (int mt = 0; mt < 2; mt++)
#pragma unroll
                    for (int nt = 0; nt < 4; nt++) sacc[mt][nt] = (f32x4){0.f, 0.f, 0.f, 0.f};
                __builtin_amdgcn_s_setprio(1);
#pragma unroll
                for (int nt = 0; nt < 4; nt++) {
                    int rr = nt * 16 + ln;
#pragma unroll
                    for (int kc = 0; kc < 2; kc++) {
                        int unit = (kc * 4 + kq) ^ (rr & 7);
                        bf16x8 bk = *reinterpret_cast<const bf16x8*>(&Kt[buf][rr * 64 + unit * 8]);
#pragma unroll
                        for (int mt = 0; mt < 2; mt++)
                            sacc[mt][nt] = __builtin_amdgcn_mfma_f32_16x16x32_bf16(bk, aq[mt][kc], sacc[mt][nt], 0, 0, 0);
                    }
                }
                __builtin_amdgcn_s_setprio(0);

                // ---- causal mask (logits already in log2-scale via Q) ----
                if (kv0 + 63 > q0) {
#pragma unroll
                    for (int mt = 0; mt < 2; mt++) {
                        int q = q0 + mt * 16 + ln;
#pragma unroll
                        for (int nt = 0; nt < 4; nt++)
#pragma unroll
                            for (int j = 0; j < 4; j++) {
                                int k = kv0 + nt * 16 + kq * 4 + j;
                                if (k > q) sacc[mt][nt][j] = -1e30f;
                            }
                    }
                }

                // ---- row max: 16 in-lane + xor16/32 ----
                float mloc[2];
#pragma unroll
                for (int mt = 0; mt < 2; mt++) {
                    f32x4 m4 = sacc[mt][0];
#pragma unroll
                    for (int nt = 1; nt < 4; nt++) {
                        m4[0] = fmaxf(m4[0], sacc[mt][nt][0]);
                        m4[1] = fmaxf(m4[1], sacc[mt][nt][1]);
                        m4[2] = fmaxf(m4[2], sacc[mt][nt][2]);
                        m4[3] = fmaxf(m4[3], sacc[mt][nt][3]);
                    }
                    mloc[mt] = fmaxf(fmaxf(m4[0], m4[1]), fmaxf(m4[2], m4[3]));
                }
#pragma unroll
                for (int mt = 0; mt < 2; mt++) {
                    mloc[mt] = fmaxf(mloc[mt], __shfl_xor(mloc[mt], 16));
                    mloc[mt] = fmaxf(mloc[mt], __shfl_xor(mloc[mt], 32));
                }

                // ---- defer-max (T13): skip rescale when growth <= 8 (log2) ----
                bool needscale = !__all((mloc[0] <= m_r[0] + 8.0f) && (mloc[1] <= m_r[1] + 8.0f));
                float so[2] = {1.f, 1.f};
                if (needscale) {
#pragma unroll
                    for (int mt = 0; mt < 2; mt++) {
                        float mn = fmaxf(m_r[mt], mloc[mt]);
                        so[mt] = exp2f(m_r[mt] - mn);
                        m_r[mt] = mn;
                    }
                }

                // ---- P = exp2(S - m); row sum ----
                float rs[2] = {0.f, 0.f};
#pragma unroll
                for (int mt = 0; mt < 2; mt++)
#pragma unroll
                    for (int nt = 0; nt < 4; nt++)
#pragma unroll
                        for (int j = 0; j < 4; j++) {
                            float p = exp2f(sacc[mt][nt][j] - m_r[mt]);
                            sacc[mt][nt][j] = p;
                            rs[mt] += p;
                        }
#pragma unroll
                for (int mt = 0; mt < 2; mt++) {
                    rs[mt] += __shfl_xor(rs[mt], 16);
                    rs[mt] += __shfl_xor(rs[mt], 32);
                    l_r[mt] = l_r[mt] * so[mt] + rs[mt];
                }

                // ---- rescale O (skip when deferred) ----
                if (needscale) {
                    float so_o[2][4];
#pragma unroll
                    for (int mt = 0; mt < 2; mt++)
#pragma unroll
                        for (int j = 0; j < 4; j++)
                            so_o[mt][j] = __shfl(so[mt], kq * 4 + j, 16);
#pragma unroll
                    for (int mt = 0; mt < 2; mt++)
#pragma unroll
                        for (int nt = 0; nt < 4; nt++)
#pragma unroll
                            for (int j = 0; j < 4; j++)
                                oacc[mt][nt][j] *= so_o[mt][j];
                }

                // ---- P -> LDS as [q][k], packed 8B writes ----
#pragma unroll
                for (int mt = 0; mt < 2; mt++)
#pragma unroll
                    for (int nt = 0; nt < 4; nt++) {
                        u16x4 o;
#pragma unroll
                        for (int j = 0; j < 4; j++) o[j] = f2bf(sacc[mt][nt][j]);
                        *reinterpret_cast<u16x4*>(&P_lds[wave][mt * 16 + ln][nt * 16 + kq * 4]) = o;
                    }
                asm volatile("s_waitcnt lgkmcnt(0)" ::: "memory");
                __builtin_amdgcn_sched_barrier(0);

                bf16x8 pa[2][2];
#pragma unroll
                for (int mt = 0; mt < 2; mt++)
#pragma unroll
                    for (int kc = 0; kc < 2; kc++)
                        pa[mt][kc] = *reinterpret_cast<const bf16x8*>(&P_lds[wave][mt * 16 + ln][kc * 32 + kq * 8]);

                // ---- PV (unswapped; oacc col=d, row=q) ----
                __builtin_amdgcn_s_setprio(1);
#pragma unroll
                for (int nt = 0; nt < 4; nt++) {
                    int rr = nt * 16 + ln;
#pragma unroll
                    for (int kc = 0; kc < 2; kc++) {
                        int unit = (kc * 4 + kq) ^ (rr & 7);
                        bf16x8 bv = *reinterpret_cast<const bf16x8*>(&Vt[buf][rr * 64 + unit * 8]);
#pragma unroll
                        for (int mt = 0; mt < 2; mt++)
                            oacc[mt][nt] = __builtin_amdgcn_mfma_f32_16x16x32_bf16(pa[mt][kc], bv, oacc[mt][nt], 0, 0, 0);
                    }
                }
                __builtin_amdgcn_s_setprio(0);
            }
            __syncthreads();
        }

        // epilogue: redistribute l to o-space once, divide, store
        float lo[2][4];
#pragma unroll
        for (int mt = 0; mt < 2; mt++)
#pragma unroll
            for (int j = 0; j < 4; j++)
                lo[mt][j] = __shfl(l_r[mt], kq * 4 + j, 16);
#pragma unroll
        for (int mt = 0; mt < 2; mt++)
#pragma unroll
            for (int nt = 0; nt < 4; nt++)
#pragma unroll
                for (int j = 0; j < 4; j++) {
                    int row = q0 + mt * 16 + kq * 4 + j;
                    float v = oacc[mt][nt][j] / lo[mt][j];
                    O[((size_t)b * SLEN + row) * DMODEL + h * 64 + nt * 16 + ln] = f2bf(v);
                }
        __syncthreads();  // strip B restages buf0 next
    }
}

// ---- Output projection: out = O @ Wo^T, fp32 result ----
__global__ __launch_bounds__(256) void out_gemm(
    const unsigned short* __restrict__ A, const unsigned short* __restrict__ Wo,
    float* __restrict__ out)
{
    __shared__ alignas(16) unsigned short As[128 * 64];
    __shared__ alignas(16) unsigned short Bs[128 * 64];
    int tid = threadIdx.x, lane = tid & 63, wave = tid >> 6;
    int ln = lane & 15, kq = lane >> 4;
    int wr = wave >> 1, wc = wave & 1;
    int m0 = blockIdx.x * 128;
    int n0 = blockIdx.y * 128;

    f32x4 acc[4][4];
    gemm128_core(A, Wo, m0, n0, tid, acc, As, Bs);

    int m0w = m0 + wr * 64, n0w = n0 + wc * 64;
#pragma unroll
    for (int mt = 0; mt < 4; mt++)
#pragma unroll
        for (int nt = 0; nt < 4; nt++)
#pragma unroll
            for (int j = 0; j < 4; j++) {
                int m = m0w + mt * 16 + kq * 4 + j;
                int n = n0w + nt * 16 + ln;
                out[(size_t)m * DMODEL + n] = acc[mt][nt][j];
            }
}

extern "C" void kernel_launch(void* const* d_in, const int* in_sizes, int n_in,
                              void* d_out, int out_size, void* d_ws, size_t ws_size,
                              hipStream_t stream) {
    const float* x  = (const float*)d_in[0];
    const int* tok  = (const int*)d_in[1];
    const float* wq = (const float*)d_in[2];
    const float* wk = (const float*)d_in[3];
    const float* wv = (const float*)d_in[4];
    const float* wo = (const float*)d_in[5];
    float* out = (float*)d_out;

    const size_t XB_OFF = 0;
    const size_t WQ_OFF = 16777216;
    const size_t WK_OFF = 18874368;
    const size_t WV_OFF = 20971520;
    const size_t WO_OFF = 23068672;
    const size_t Q_OFF  = 25165824;
    const size_t K_OFF  = 41943040;
    const size_t VT_OFF = 58720256;
    const size_t O_OFF  = 75497472;
    const size_t CS_OFF = 92274688;
    const size_t SN_OFF = 92536832;
    const size_t WS_NEEDED = 92798976;
    if (ws_size < WS_NEEDED) return;

    char* ws = (char*)d_ws;
    unsigned short* Xb  = (unsigned short*)(ws + XB_OFF);
    unsigned short* Wqb = (unsigned short*)(ws + WQ_OFF);
    unsigned short* Wkb = (unsigned short*)(ws + WK_OFF);
    unsigned short* Wvb = (unsigned short*)(ws + WV_OFF);
    unsigned short* Wob = (unsigned short*)(ws + WO_OFF);
    unsigned short* Qb  = (unsigned short*)(ws + Q_OFF);
    unsigned short* Kb  = (unsigned short*)(ws + K_OFF);
    unsigned short* VTb = (unsigned short*)(ws + VT_OFF);
    unsigned short* Ob  = (unsigned short*)(ws + O_OFF);
    float* cs_tab = (float*)(ws + CS_OFF);
    float* sn_tab = (float*)(ws + SN_OFF);

    cvt_f32_bf16<<<8192, 256, 0, stream>>>(x,  Xb,  MROWS * DMODEL);
    cvt_f32_bf16<<<1024, 256, 0, stream>>>(wq, Wqb, DMODEL * DMODEL);
    cvt_f32_bf16<<<1024, 256, 0, stream>>>(wk, Wkb, DMODEL * DMODEL);
    cvt_f32_bf16<<<1024, 256, 0, stream>>>(wv, Wvb, DMODEL * DMODEL);
    cvt_f32_bf16<<<1024, 256, 0, stream>>>(wo, Wob, DMODEL * DMODEL);
    rope_table<<<256, 256, 0, stream>>>(tok, cs_tab, sn_tab);

    qkv_gemm<<<dim3(MROWS / 128, DMODEL / 128, 3), 256, 0, stream>>>(
        Xb, Wqb, Wkb, Wvb, cs_tab, sn_tab, Qb, Kb, VTb);

    attn_kernel<<<dim3(SLEN / 256, NHEADS, BATCH), 256, 0, stream>>>(Qb, Kb, VTb, Ob);

    out_gemm<<<dim3(MROWS / 128, DMODEL / 128, 1), 256, 0, stream>>>(Ob, Wob, out);
}

// Round 5
// 214.575 us; speedup vs baseline: 3.5574x; 1.0776x over previous
//
#include <hip/hip_runtime.h>

#define BATCH 4
#define SLEN 2048
#define DMODEL 1024
#define NHEADS 16
#define DK 64
#define MROWS (BATCH * SLEN)  // 8192
#define NQB 16                // SLEN/128 q-strips
#define SCALE_LOG2E 0.1803368801111731f  // 0.125 * log2(e), folded into Q

typedef short bf16x8 __attribute__((ext_vector_type(8)));
typedef unsigned short u16x4 __attribute__((ext_vector_type(4)));
typedef float f32x4 __attribute__((ext_vector_type(4)));

__device__ __forceinline__ unsigned short f2bf(float f) {
    unsigned u = __float_as_uint(f);
    unsigned r = u + 0x7FFFu + ((u >> 16) & 1u);
    return (unsigned short)(r >> 16);
}

// packed f32x2 -> bf16x2 (single HW instr; no builtin on gfx950)
__device__ __forceinline__ unsigned pkbf(float a, float b) {
    unsigned r;
    asm volatile("v_cvt_pk_bf16_f32 %0, %1, %2" : "=v"(r) : "v"(a), "v"(b));
    return r;
}

__device__ __forceinline__ void gload_lds16(const void* g, void* l) {
    __builtin_amdgcn_global_load_lds(
        (const __attribute__((address_space(1))) void*)g,
        (__attribute__((address_space(3))) void*)l, 16, 0, 0);
}

__global__ void cvt_f32_bf16(const float* __restrict__ in, unsigned short* __restrict__ out, int n) {
    int i = (blockIdx.x * blockDim.x + threadIdx.x) * 4;
    if (i >= n) return;
    float4 v = *reinterpret_cast<const float4*>(in + i);
    u16x4 o;
    o[0] = f2bf(v.x); o[1] = f2bf(v.y); o[2] = f2bf(v.z); o[3] = f2bf(v.w);
    *reinterpret_cast<u16x4*>(out + i) = o;
}

// all 4 weight matrices in one launch (blockIdx.y selects)
__global__ void cvt_w_all(const float* __restrict__ w0, const float* __restrict__ w1,
                          const float* __restrict__ w2, const float* __restrict__ w3,
                          unsigned short* __restrict__ o0, unsigned short* __restrict__ o1,
                          unsigned short* __restrict__ o2, unsigned short* __restrict__ o3) {
    int z = blockIdx.y;
    const float* src = (z == 0) ? w0 : (z == 1) ? w1 : (z == 2) ? w2 : w3;
    unsigned short* dst = (z == 0) ? o0 : (z == 1) ? o1 : (z == 2) ? o2 : o3;
    int i = (blockIdx.x * blockDim.x + threadIdx.x) * 4;
    float4 v = *reinterpret_cast<const float4*>(src + i);
    u16x4 o;
    o[0] = f2bf(v.x); o[1] = f2bf(v.y); o[2] = f2bf(v.z); o[3] = f2bf(v.w);
    *reinterpret_cast<u16x4*>(dst + i) = o;
}

__global__ void rope_table(const int* __restrict__ tok, float* __restrict__ cs, float* __restrict__ sn) {
    int idx = blockIdx.x * blockDim.x + threadIdx.x;
    if (idx >= SLEN * 32) return;
    int s = idx >> 5, fi = idx & 31;
    float invf = powf(10000.0f, -(float)(2 * fi) / 64.0f);
    float ang = (float)tok[s] * invf;
    cs[idx] = cosf(ang);
    sn[idx] = sinf(ang);
}

// ---- m97-style 128x128 GEMM core ----
__device__ __forceinline__ void gemm128_core(
    const unsigned short* __restrict__ A, const unsigned short* __restrict__ B,
    int m0, int n0, int tid, f32x4 (&acc)[4][4],
    unsigned short* As, unsigned short* Bs)
{
    int lane = tid & 63, wave = tid >> 6;
    int ln = lane & 15, kq = lane >> 4;
    int wr = wave >> 1, wc = wave & 1;
#pragma unroll
    for (int a = 0; a < 4; a++)
#pragma unroll
        for (int b = 0; b < 4; b++) acc[a][b] = (f32x4){0.f, 0.f, 0.f, 0.f};

    for (int k0 = 0; k0 < DMODEL; k0 += 64) {
        if (k0) __syncthreads();
#pragma unroll
        for (int i = 0; i < 4; i++) {
            int s = i * 256 + tid;
            int r = s >> 3;
            int u = (s & 7) ^ (r & 7);
            gload_lds16(A + (size_t)(m0 + r) * DMODEL + k0 + u * 8, &As[(i * 256 + wave * 64) * 8]);
            gload_lds16(B + (size_t)(n0 + r) * DMODEL + k0 + u * 8, &Bs[(i * 256 + wave * 64) * 8]);
        }
        __syncthreads();

        bf16x8 af[4][2], bfr[4][2];
#pragma unroll
        for (int mt = 0; mt < 4; mt++) {
            int row = wr * 64 + mt * 16 + ln;
#pragma unroll
            for (int kc = 0; kc < 2; kc++) {
                int u = (kc * 4 + kq) ^ (row & 7);
                af[mt][kc] = *reinterpret_cast<const bf16x8*>(&As[row * 64 + u * 8]);
            }
        }
#pragma unroll
        for (int nt = 0; nt < 4; nt++) {
            int row = wc * 64 + nt * 16 + ln;
#pragma unroll
            for (int kc = 0; kc < 2; kc++) {
                int u = (kc * 4 + kq) ^ (row & 7);
                bfr[nt][kc] = *reinterpret_cast<const bf16x8*>(&Bs[row * 64 + u * 8]);
            }
        }
        __builtin_amdgcn_s_setprio(1);
#pragma unroll
        for (int kc = 0; kc < 2; kc++)
#pragma unroll
            for (int mt = 0; mt < 4; mt++)
#pragma unroll
                for (int nt = 0; nt < 4; nt++)
                    acc[mt][nt] = __builtin_amdgcn_mfma_f32_16x16x32_bf16(af[mt][kc], bfr[nt][kc], acc[mt][nt], 0, 0, 0);
        __builtin_amdgcn_s_setprio(0);
    }
}

// ---- Fused QKV projection GEMM + RoPE epilogue; Q pre-scaled by 0.125*log2e ----
__global__ __launch_bounds__(256) void qkv_gemm(
    const unsigned short* __restrict__ X,
    const unsigned short* __restrict__ Wq,
    const unsigned short* __restrict__ Wk,
    const unsigned short* __restrict__ Wv,
    const float* __restrict__ cs_tab, const float* __restrict__ sn_tab,
    unsigned short* __restrict__ Q, unsigned short* __restrict__ K,
    unsigned short* __restrict__ VT)
{
    __shared__ alignas(16) unsigned short As[128 * 64];
    __shared__ alignas(16) unsigned short Bs[128 * 64];
    int tid = threadIdx.x, lane = tid & 63, wave = tid >> 6;
    int ln = lane & 15, kq = lane >> 4;
    int wr = wave >> 1, wc = wave & 1;
    int m0 = blockIdx.x * 128;
    int n0 = blockIdx.y * 128;
    int z = blockIdx.z;
    const unsigned short* W = (z == 0) ? Wq : (z == 1) ? Wk : Wv;

    f32x4 acc[4][4];
    gemm128_core(X, W, m0, n0, tid, acc, As, Bs);

    bool isV = (z == 2);
    bool isQ = (z == 0);
    unsigned short* dstQK = (z == 0) ? Q : K;
    int m0w = m0 + wr * 64, n0w = n0 + wc * 64;
#pragma unroll
    for (int nt = 0; nt < 4; nt++) {
        int n = n0w + nt * 16 + ln;
        int h = n >> 6, d = n & 63;
        int fi = d >> 1;
#pragma unroll
        for (int mt = 0; mt < 4; mt++) {
#pragma unroll
            for (int j = 0; j < 4; j++) {
                int m = m0w + mt * 16 + kq * 4 + j;
                int b = m >> 11, s = m & (SLEN - 1);
                float v = acc[mt][nt][j];
                if (!isV) {
                    float c = cs_tab[s * 32 + fi];
                    float si = sn_tab[s * 32 + fi];
                    float p = __shfl_xor(v, 1);
                    v = (d & 1) ? (p * si + v * c) : (v * c - p * si);
                    if (isQ) v *= SCALE_LOG2E;
                    dstQK[(((size_t)(b * NHEADS + h) * SLEN + s) << 6) + d] = f2bf(v);
                } else {
                    VT[((size_t)(b * NHEADS + h) * DK + d) * SLEN + s] = f2bf(v);
                }
            }
        }
    }
}

// ---- Causal flash attention v5: pi-permuted K staging, P fully in-register ----
// pi(r) = bit shuffle [b5|b3b2|b4|b1b0]: QK^T output k-layout == PV A-fragment
// k-layout, so P needs NO cross-lane movement and NO LDS staging.
__global__ __launch_bounds__(256, 4) void attn_kernel(
    const unsigned short* __restrict__ Q, const unsigned short* __restrict__ K,
    const unsigned short* __restrict__ VT, unsigned short* __restrict__ O)
{
    __shared__ alignas(16) unsigned short Kt[2][4096];
    __shared__ alignas(16) unsigned short Vt[2][4096];

    int tid = threadIdx.x, lane = tid & 63, wave = tid >> 6;
    int ln = lane & 15, kq = lane >> 4;
    int qb = blockIdx.x;  // 0..7
    int h = blockIdx.y, b = blockIdx.z;
    size_t headoff = ((size_t)b * NHEADS + h) * SLEN * DK;
    const unsigned short* Qh = Q + headoff;
    const unsigned short* Kh = K + headoff;
    const unsigned short* Vh = VT + headoff;  // [64][SLEN]

    auto stage = [&](int buf, int t) {
        int kv0 = t << 6;
#pragma unroll
        for (int i = 0; i < 2; i++) {
            int s = i * 256 + tid;
            int r = s >> 3;
            int cb = (s & 7) ^ (r & 7);
            // K rows pi-permuted: pi(r) = [b5 | b3 b2 | b4 | b1 b0]
            int rp = ((r >> 5) << 5) | (((r >> 2) & 3) << 3) | (((r >> 4) & 1) << 2) | (r & 3);
            gload_lds16(Kh + (size_t)(kv0 + rp) * DK + cb * 8,
                        &Kt[buf][(i * 256 + wave * 64) * 8]);
            gload_lds16(Vh + (size_t)r * SLEN + kv0 + cb * 8,
                        &Vt[buf][(i * 256 + wave * 64) * 8]);
        }
    };

    for (int sid = 0; sid < 2; sid++) {
        int qs = sid ? qb : (NQB - 1 - qb);
        int q0 = qs * 128 + wave * 32;

        bf16x8 aq[2][2];
#pragma unroll
        for (int mt = 0; mt < 2; mt++)
#pragma unroll
            for (int kc = 0; kc < 2; kc++)
                aq[mt][kc] = *reinterpret_cast<const bf16x8*>(
                    Qh + (size_t)(q0 + mt * 16 + ln) * DK + kc * 32 + kq * 8);

        f32x4 oacc[2][4];
#pragma unroll
        for (int mt = 0; mt < 2; mt++)
#pragma unroll
            for (int nt = 0; nt < 4; nt++) oacc[mt][nt] = (f32x4){0.f, 0.f, 0.f, 0.f};
        float m_r[2] = {-1e30f, -1e30f};
        float l_r[2] = {0.f, 0.f};

        int tmax_w = (q0 + 31) >> 6;
        int ntiles = 2 * qs + 2;

        stage(0, 0);
        __syncthreads();

        for (int t = 0; t < ntiles; t++) {
            int buf = t & 1;
            if (t + 1 < ntiles) stage(buf ^ 1, t + 1);

            if (t <= tmax_w) {
                int kv0 = t << 6;
                // ---- QK^T swapped: lane(ln,kq) sacc[mt][nt][j] holds
                // S[q = q0+mt*16+ln][k = kv0 + (nt>>1)*32 + kq*8 + (nt&1)*4 + j] ----
                f32x4 sacc[2][4];
#pragma unroll
                for (int mt = 0; mt < 2; mt++)
#pragma unroll
                    for (int nt = 0; nt < 4; nt++) sacc[mt][nt] = (f32x4){0.f, 0.f, 0.f, 0.f};
                __builtin_amdgcn_s_setprio(1);
#pragma unroll
                for (int nt = 0; nt < 4; nt++) {
                    int rr = nt * 16 + ln;
#pragma unroll
                    for (int kc = 0; kc < 2; kc++) {
                        int unit = (kc * 4 + kq) ^ (rr & 7);
                        bf16x8 bk = *reinterpret_cast<const bf16x8*>(&Kt[buf][rr * 64 + unit * 8]);
#pragma unroll
                        for (int mt = 0; mt < 2; mt++)
                            sacc[mt][nt] = __builtin_amdgcn_mfma_f32_16x16x32_bf16(bk, aq[mt][kc], sacc[mt][nt], 0, 0, 0);
                    }
                }
                __builtin_amdgcn_s_setprio(0);

                // ---- causal mask (pi-mapped k index) ----
                if (kv0 + 63 > q0) {
#pragma unroll
                    for (int mt = 0; mt < 2; mt++) {
                        int q = q0 + mt * 16 + ln;
#pragma unroll
                        for (int nt = 0; nt < 4; nt++)
#pragma unroll
                            for (int j = 0; j < 4; j++) {
                                int k = kv0 + (nt >> 1) * 32 + kq * 8 + (nt & 1) * 4 + j;
                                if (k > q) sacc[mt][nt][j] = -1e30f;
                            }
                    }
                }

                // ---- row max: in-lane + xor16/32 ----
                float mloc[2];
#pragma unroll
                for (int mt = 0; mt < 2; mt++) {
                    f32x4 m4 = sacc[mt][0];
#pragma unroll
                    for (int nt = 1; nt < 4; nt++) {
                        m4[0] = fmaxf(m4[0], sacc[mt][nt][0]);
                        m4[1] = fmaxf(m4[1], sacc[mt][nt][1]);
                        m4[2] = fmaxf(m4[2], sacc[mt][nt][2]);
                        m4[3] = fmaxf(m4[3], sacc[mt][nt][3]);
                    }
                    mloc[mt] = fmaxf(fmaxf(m4[0], m4[1]), fmaxf(m4[2], m4[3]));
                }
#pragma unroll
                for (int mt = 0; mt < 2; mt++) {
                    mloc[mt] = fmaxf(mloc[mt], __shfl_xor(mloc[mt], 16));
                    mloc[mt] = fmaxf(mloc[mt], __shfl_xor(mloc[mt], 32));
                }

                // ---- defer-max (T13) ----
                bool needscale = !__all((mloc[0] <= m_r[0] + 8.0f) && (mloc[1] <= m_r[1] + 8.0f));
                float so[2] = {1.f, 1.f};
                if (needscale) {
#pragma unroll
                    for (int mt = 0; mt < 2; mt++) {
                        float mn = fmaxf(m_r[mt], mloc[mt]);
                        so[mt] = exp2f(m_r[mt] - mn);
                        m_r[mt] = mn;
                    }
                }

                // ---- P = exp2(S - m); row sum ----
                float rs[2] = {0.f, 0.f};
#pragma unroll
                for (int mt = 0; mt < 2; mt++)
#pragma unroll
                    for (int nt = 0; nt < 4; nt++)
#pragma unroll
                        for (int j = 0; j < 4; j++) {
                            float p = exp2f(sacc[mt][nt][j] - m_r[mt]);
                            sacc[mt][nt][j] = p;
                            rs[mt] += p;
                        }
#pragma unroll
                for (int mt = 0; mt < 2; mt++) {
                    rs[mt] += __shfl_xor(rs[mt], 16);
                    rs[mt] += __shfl_xor(rs[mt], 32);
                    l_r[mt] = l_r[mt] * so[mt] + rs[mt];
                }

                // ---- rescale O (skip when deferred) ----
                if (needscale) {
                    float so_o[2][4];
#pragma unroll
                    for (int mt = 0; mt < 2; mt++)
#pragma unroll
                        for (int j = 0; j < 4; j++)
                            so_o[mt][j] = __shfl(so[mt], kq * 4 + j, 16);
#pragma unroll
                    for (int mt = 0; mt < 2; mt++)
#pragma unroll
                        for (int nt = 0; nt < 4; nt++)
#pragma unroll
                            for (int j = 0; j < 4; j++)
                                oacc[mt][nt][j] *= so_o[mt][j];
                }

                // ---- P -> PV A-fragments: pure in-register (pi made layouts match) ----
                // pa[mt][kc] elems 0..3 = sacc[mt][2kc][0..3], 4..7 = sacc[mt][2kc+1][0..3]
                bf16x8 pa[2][2];
#pragma unroll
                for (int mt = 0; mt < 2; mt++)
#pragma unroll
                    for (int kc = 0; kc < 2; kc++) {
                        union { unsigned u[4]; bf16x8 v; } r;
                        r.u[0] = pkbf(sacc[mt][2 * kc][0], sacc[mt][2 * kc][1]);
                        r.u[1] = pkbf(sacc[mt][2 * kc][2], sacc[mt][2 * kc][3]);
                        r.u[2] = pkbf(sacc[mt][2 * kc + 1][0], sacc[mt][2 * kc + 1][1]);
                        r.u[3] = pkbf(sacc[mt][2 * kc + 1][2], sacc[mt][2 * kc + 1][3]);
                        pa[mt][kc] = r.v;
                    }

                // ---- PV ----
                __builtin_amdgcn_s_setprio(1);
#pragma unroll
                for (int nt = 0; nt < 4; nt++) {
                    int rr = nt * 16 + ln;
#pragma unroll
                    for (int kc = 0; kc < 2; kc++) {
                        int unit = (kc * 4 + kq) ^ (rr & 7);
                        bf16x8 bv = *reinterpret_cast<const bf16x8*>(&Vt[buf][rr * 64 + unit * 8]);
#pragma unroll
                        for (int mt = 0; mt < 2; mt++)
                            oacc[mt][nt] = __builtin_amdgcn_mfma_f32_16x16x32_bf16(pa[mt][kc], bv, oacc[mt][nt], 0, 0, 0);
                    }
                }
                __builtin_amdgcn_s_setprio(0);
            }
            __syncthreads();
        }

        // epilogue: redistribute l to o-space once, divide, store
        float lo[2][4];
#pragma unroll
        for (int mt = 0; mt < 2; mt++)
#pragma unroll
            for (int j = 0; j < 4; j++)
                lo[mt][j] = __shfl(l_r[mt], kq * 4 + j, 16);
#pragma unroll
        for (int mt = 0; mt < 2; mt++)
#pragma unroll
            for (int nt = 0; nt < 4; nt++)
#pragma unroll
                for (int j = 0; j < 4; j++) {
                    int row = q0 + mt * 16 + kq * 4 + j;
                    float v = oacc[mt][nt][j] / lo[mt][j];
                    O[((size_t)b * SLEN + row) * DMODEL + h * 64 + nt * 16 + ln] = f2bf(v);
                }
        __syncthreads();  // strip B restages buf0 next
    }
}

// ---- Output projection: out = O @ Wo^T, fp32 result ----
__global__ __launch_bounds__(256) void out_gemm(
    const unsigned short* __restrict__ A, const unsigned short* __restrict__ Wo,
    float* __restrict__ out)
{
    __shared__ alignas(16) unsigned short As[128 * 64];
    __shared__ alignas(16) unsigned short Bs[128 * 64];
    int tid = threadIdx.x, lane = tid & 63, wave = tid >> 6;
    int ln = lane & 15, kq = lane >> 4;
    int wr = wave >> 1, wc = wave & 1;
    int m0 = blockIdx.x * 128;
    int n0 = blockIdx.y * 128;

    f32x4 acc[4][4];
    gemm128_core(A, Wo, m0, n0, tid, acc, As, Bs);

    int m0w = m0 + wr * 64, n0w = n0 + wc * 64;
#pragma unroll
    for (int mt = 0; mt < 4; mt++)
#pragma unroll
        for (int nt = 0; nt < 4; nt++)
#pragma unroll
            for (int j = 0; j < 4; j++) {
                int m = m0w + mt * 16 + kq * 4 + j;
                int n = n0w + nt * 16 + ln;
                out[(size_t)m * DMODEL + n] = acc[mt][nt][j];
            }
}

extern "C" void kernel_launch(void* const* d_in, const int* in_sizes, int n_in,
                              void* d_out, int out_size, void* d_ws, size_t ws_size,
                              hipStream_t stream) {
    const float* x  = (const float*)d_in[0];
    const int* tok  = (const int*)d_in[1];
    const float* wq = (const float*)d_in[2];
    const float* wk = (const float*)d_in[3];
    const float* wv = (const float*)d_in[4];
    const float* wo = (const float*)d_in[5];
    float* out = (float*)d_out;

    const size_t XB_OFF = 0;
    const size_t WQ_OFF = 16777216;
    const size_t WK_OFF = 18874368;
    const size_t WV_OFF = 20971520;
    const size_t WO_OFF = 23068672;
    const size_t Q_OFF  = 25165824;
    const size_t K_OFF  = 41943040;
    const size_t VT_OFF = 58720256;
    const size_t O_OFF  = 75497472;
    const size_t CS_OFF = 92274688;
    const size_t SN_OFF = 92536832;
    const size_t WS_NEEDED = 92798976;
    if (ws_size < WS_NEEDED) return;

    char* ws = (char*)d_ws;
    unsigned short* Xb  = (unsigned short*)(ws + XB_OFF);
    unsigned short* Wqb = (unsigned short*)(ws + WQ_OFF);
    unsigned short* Wkb = (unsigned short*)(ws + WK_OFF);
    unsigned short* Wvb = (unsigned short*)(ws + WV_OFF);
    unsigned short* Wob = (unsigned short*)(ws + WO_OFF);
    unsigned short* Qb  = (unsigned short*)(ws + Q_OFF);
    unsigned short* Kb  = (unsigned short*)(ws + K_OFF);
    unsigned short* VTb = (unsigned short*)(ws + VT_OFF);
    unsigned short* Ob  = (unsigned short*)(ws + O_OFF);
    float* cs_tab = (float*)(ws + CS_OFF);
    float* sn_tab = (float*)(ws + SN_OFF);

    cvt_f32_bf16<<<8192, 256, 0, stream>>>(x, Xb, MROWS * DMODEL);
    cvt_w_all<<<dim3(1024, 4), 256, 0, stream>>>(wq, wk, wv, wo, Wqb, Wkb, Wvb, Wob);
    rope_table<<<256, 256, 0, stream>>>(tok, cs_tab, sn_tab);

    qkv_gemm<<<dim3(MROWS / 128, DMODEL / 128, 3), 256, 0, stream>>>(
        Xb, Wqb, Wkb, Wvb, cs_tab, sn_tab, Qb, Kb, VTb);

    attn_kernel<<<dim3(SLEN / 256, NHEADS, BATCH), 256, 0, stream>>>(Qb, Kb, VTb, Ob);

    out_gemm<<<dim3(MROWS / 128, DMODEL / 128, 1), 256, 0, stream>>>(Ob, Wob, out);
}